// Round 6
// baseline (432.177 us; speedup 1.0000x reference)
//
#include <hip/hip_runtime.h>
#include <math.h>

#define NN 10000
#define NE 160000

// ---------------- CSR build ----------------

__global__ __launch_bounds__(256) void deg_kernel(const int* __restrict__ src,
                                                  const int* __restrict__ dst,
                                                  int* __restrict__ deg,
                                                  int* __restrict__ cnt, int E) {
  int e = blockIdx.x * 256 + threadIdx.x;
  if (e < E) {
    atomicAdd(&deg[src[e]], 1);
    atomicAdd(&cnt[dst[e]], 1);
  }
}

// fused: dinv (from deg-by-src) + exclusive scan of cnt (by dst) -> off
__global__ __launch_bounds__(1024) void scan_dinv_kernel(const int* __restrict__ cnt,
                                                         int* __restrict__ off,
                                                         const int* __restrict__ deg,
                                                         float* __restrict__ dinv, int n) {
  __shared__ int sh[1024];
  int t = threadIdx.x;
  for (int i = t; i < n; i += 1024) {
    int d = deg[i];
    dinv[i] = d > 0 ? 1.0f / sqrtf((float)d) : 0.0f;
  }
  int per = (n + 1023) / 1024;
  int base = t * per;
  int sum = 0;
  for (int i = 0; i < per; i++) {
    int idx = base + i;
    if (idx < n) sum += cnt[idx];
  }
  sh[t] = sum;
  __syncthreads();
  for (int d = 1; d < 1024; d <<= 1) {
    int v = (t >= d) ? sh[t - d] : 0;
    __syncthreads();
    if (t >= d) sh[t] += v;
    __syncthreads();
  }
  int run = (t > 0) ? sh[t - 1] : 0;
  for (int i = 0; i < per; i++) {
    int idx = base + i;
    if (idx < n) { off[idx] = run; run += cnt[idx]; }
  }
  if (t == 0) off[n] = sh[1023];
}

__global__ __launch_bounds__(256) void fill_kernel(const int* __restrict__ src,
                                                   const int* __restrict__ dst,
                                                   const float* __restrict__ dinv,
                                                   const int* __restrict__ off,
                                                   int* __restrict__ pos,
                                                   int* __restrict__ csrc,
                                                   float* __restrict__ cw, int E) {
  int e = blockIdx.x * 256 + threadIdx.x;
  if (e < E) {
    int s = src[e], d = dst[e];
    int slot = off[d] + atomicAdd(&pos[d], 1);
    csrc[slot] = s;
    cw[slot] = -dinv[s] * dinv[d];
  }
}

// ---------------- weight concat (both push-through layers, one launch) -------
// Wc [Fin][3*Fp]: cols [0,Fp)=W0-W2, [Fp,2Fp)=W1, [2Fp,3Fp)=W2 ; pad cols zero

__device__ __forceinline__ void wcat_one(const float* __restrict__ W,
                                         float* __restrict__ Wc,
                                         int i, int Fin, int F, int Fp) {
  int w3 = 3 * Fp;
  int row = i / w3;
  int c = i - row * w3;
  int sec = c / Fp;
  int f = c - sec * Fp;
  float v = 0.0f;
  if (f < F) {
    if (sec == 0)      v = W[row * F + f] - W[2 * Fin * F + row * F + f];
    else if (sec == 1) v = W[Fin * F + row * F + f];
    else               v = W[2 * Fin * F + row * F + f];
  }
  Wc[i] = v;
}

__global__ __launch_bounds__(256) void wcat2_kernel(const float* __restrict__ W1,
                                                    float* __restrict__ wc1,
                                                    const float* __restrict__ W5,
                                                    float* __restrict__ wc5) {
  int i = blockIdx.x * 256 + threadIdx.x;
  const int t1 = 782 * 48;
  const int t5 = 128 * 60;
  if (i < t1) {
    wcat_one(W1, wc1, i, 782, 16, 16);
  } else if (i < t1 + t5) {
    wcat_one(W5, wc5, i - t1, 128, 19, 20);
  }
}

// ---------------- GEMM v6: v5 structure, scratch-spill bug fixed -------------
// 512 rows/block (2 rows/thread), TN cols. W k-slice in LDS (wave-uniform
// ds_read_b128 broadcast). X prefetched chunk-ahead into a by-value struct of
// NAMED float4 fields (no runtime-indexed local arrays, no address-taken
// locals) -> everything stays in VGPRs. Partials to P[z][M*Nd], plain stores.

struct X8 {
  float4 v0, v1, v2, v3, v4, v5, v6, v7;
};

template <bool AL16>
__device__ __forceinline__ float4 ld_row(const float* __restrict__ X, int ldx,
                                         int gr, int M, int kc, int kq4, int kend) {
  float4 v = make_float4(0.f, 0.f, 0.f, 0.f);
  if (gr < M) {
    const float* xp = X + (size_t)gr * ldx + kc + kq4;
    if (kc + 16 <= kend) {
      if (AL16) {
        v = *(const float4*)xp;
      } else {  // rows only 8B-aligned (ldx=782)
        float2 a = *(const float2*)xp;
        float2 b = *(const float2*)(xp + 2);
        v = make_float4(a.x, a.y, b.x, b.y);
      }
    } else {
      int rem = kend - kc;  // 1..15
      if (kq4 + 0 < rem) v.x = xp[0];
      if (kq4 + 1 < rem) v.y = xp[1];
      if (kq4 + 2 < rem) v.z = xp[2];
      if (kq4 + 3 < rem) v.w = xp[3];
    }
  }
  return v;
}

template <bool AL16>
__device__ __forceinline__ X8 load_chunk(const float* __restrict__ X, int ldx,
                                         int row0, int rbase, int M,
                                         int kc, int kq4, int kend) {
  X8 r;
  r.v0 = ld_row<AL16>(X, ldx, row0 + rbase +   0, M, kc, kq4, kend);
  r.v1 = ld_row<AL16>(X, ldx, row0 + rbase +  64, M, kc, kq4, kend);
  r.v2 = ld_row<AL16>(X, ldx, row0 + rbase + 128, M, kc, kq4, kend);
  r.v3 = ld_row<AL16>(X, ldx, row0 + rbase + 192, M, kc, kq4, kend);
  r.v4 = ld_row<AL16>(X, ldx, row0 + rbase + 256, M, kc, kq4, kend);
  r.v5 = ld_row<AL16>(X, ldx, row0 + rbase + 320, M, kc, kq4, kend);
  r.v6 = ld_row<AL16>(X, ldx, row0 + rbase + 384, M, kc, kq4, kend);
  r.v7 = ld_row<AL16>(X, ldx, row0 + rbase + 448, M, kc, kq4, kend);
  return r;
}

template <int TN, int MAXKC, bool AL16>
__global__ __launch_bounds__(256, 2) void gemm_v6_kernel(
    const float* __restrict__ X, int ldx,
    const float* __restrict__ W, int ldw,
    float* __restrict__ P,
    int M, int Kd, int kchunk, int Nd) {
  __shared__ float Xs[512 * 20];
  __shared__ float Ws[MAXKC * TN];
  int t = threadIdx.x;
  int row0 = blockIdx.x * 512;
  int col0 = blockIdx.y * TN;
  int k0 = blockIdx.z * kchunk;
  int kend = k0 + kchunk;
  if (kend > Kd) kend = Kd;
  P += (size_t)blockIdx.z * M * Nd;

  // ---- stage W slice [k0,kend) x TN (zero-filled to MAXKC) ----
  constexpr int W4 = TN / 4;
  for (int idx = t; idx < MAXKC * W4; idx += 256) {
    int wk = idx / W4;
    int wc = (idx - wk * W4) * 4;
    float4 wv = make_float4(0.f, 0.f, 0.f, 0.f);
    if (k0 + wk < kend)
      wv = *(const float4*)(W + (size_t)(k0 + wk) * ldw + col0 + wc);
    *(float4*)(Ws + wk * TN + wc) = wv;
  }

  float acc0[TN], acc1[TN];
#pragma unroll
  for (int c = 0; c < TN; c++) { acc0[c] = 0.f; acc1[c] = 0.f; }

  int rbase = t >> 2;      // 0..63
  int kq4 = (t & 3) << 2;  // 0,4,8,12
  int nchunks = (kend - k0 + 15) >> 4;

  X8 cur = load_chunk<AL16>(X, ldx, row0, rbase, M, k0, kq4, kend);
  for (int ci = 0; ci < nchunks; ci++) {
    X8 nxt = cur;
    if (ci + 1 < nchunks)
      nxt = load_chunk<AL16>(X, ldx, row0, rbase, M, k0 + (ci + 1) * 16, kq4, kend);
    __syncthreads();  // previous compute done (Xs free); Ws ready on ci==0
    {
      float* d0 = Xs + rbase * 20 + kq4;
      *(float4*)(d0 +  0 * 64 * 20) = cur.v0;
      *(float4*)(d0 +  1 * 64 * 20) = cur.v1;
      *(float4*)(d0 +  2 * 64 * 20) = cur.v2;
      *(float4*)(d0 +  3 * 64 * 20) = cur.v3;
      *(float4*)(d0 +  4 * 64 * 20) = cur.v4;
      *(float4*)(d0 +  5 * 64 * 20) = cur.v5;
      *(float4*)(d0 +  6 * 64 * 20) = cur.v6;
      *(float4*)(d0 +  7 * 64 * 20) = cur.v7;
    }
    __syncthreads();  // Xs visible
    int kb = ci << 4;
#pragma unroll
    for (int kg = 0; kg < 4; kg++) {
      float4 xa = *(const float4*)(Xs + t * 20 + (kg << 2));
      float4 xb = *(const float4*)(Xs + (t + 256) * 20 + (kg << 2));
      float xs0[4] = {xa.x, xa.y, xa.z, xa.w};
      float xs1[4] = {xb.x, xb.y, xb.z, xb.w};
#pragma unroll
      for (int j = 0; j < 4; j++) {
        const float* wr = Ws + (kb + (kg << 2) + j) * TN;
#pragma unroll
        for (int c = 0; c < TN; c += 4) {
          float4 wv = *(const float4*)(wr + c);  // wave-uniform -> broadcast
          acc0[c + 0] += xs0[j] * wv.x; acc0[c + 1] += xs0[j] * wv.y;
          acc0[c + 2] += xs0[j] * wv.z; acc0[c + 3] += xs0[j] * wv.w;
          acc1[c + 0] += xs1[j] * wv.x; acc1[c + 1] += xs1[j] * wv.y;
          acc1[c + 2] += xs1[j] * wv.z; acc1[c + 3] += xs1[j] * wv.w;
        }
      }
    }
    cur = nxt;
  }

  // ---- store partials (explicit, no pointer-select over acc arrays) ----
  {
    int r = row0 + t;
    if (r < M) {
      float* pr = P + (size_t)r * Nd + col0;
#pragma unroll
      for (int c = 0; c < TN; c += 4)
        *(float4*)(pr + c) = make_float4(acc0[c], acc0[c + 1], acc0[c + 2], acc0[c + 3]);
    }
  }
  {
    int r = row0 + t + 256;
    if (r < M) {
      float* pr = P + (size_t)r * Nd + col0;
#pragma unroll
      for (int c = 0; c < TN; c += 4)
        *(float4*)(pr + c) = make_float4(acc1[c], acc1[c + 1], acc1[c + 2], acc1[c + 3]);
    }
  }
}

// fused k-split reduce + bias + relu: Y[r*ldy+c] = act(sum_j P[j][r*Nd+c] + bias[c])
__global__ __launch_bounds__(256) void reduce_bias_kernel(
    const float* __restrict__ P, float* __restrict__ Y,
    const float* __restrict__ bias,
    int M, int Nd, int ldy, int nsplit, int relu) {
  int i = blockIdx.x * 256 + threadIdx.x;
  int total = M * Nd;
  if (i >= total) return;
  float s = 0.f;
  for (int j = 0; j < nsplit; j++) s += P[(size_t)j * total + i];
  int r = i / Nd, c = i - r * Nd;
  if (bias) s += bias[c];
  if (relu) s = fmaxf(s, 0.f);
  Y[(size_t)r * ldy + c] = s;
}

// ---------------- SpMM: wave-per-node (optionally fused softmax) ------------

__global__ __launch_bounds__(256) void spmm_kernel(
    const int* __restrict__ off,
    const int* __restrict__ csrc,
    const float* __restrict__ cw,
    const float* __restrict__ X, int ldx,
    float* __restrict__ Y, int ldy,
    const float* __restrict__ add, int lda,
    const float* __restrict__ bias,
    float alpha, float beta,
    int n, int C_log2, int Fstore, int relu, int do_softmax) {
  int wave_in_blk = threadIdx.x >> 6;
  int lane = threadIdx.x & 63;
  int node = blockIdx.x * 4 + wave_in_blk;
  if (node >= n) return;
  int C = 1 << C_log2;
  int chunk = lane & (C - 1);
  int eslot = lane >> C_log2;
  int Epar = 64 >> C_log2;

  int j0 = off[node], j1 = off[node + 1];
  float sx = 0.f, sy = 0.f, sz = 0.f, sw = 0.f;
  for (int j = j0 + eslot; j < j1; j += Epar) {
    int sn = csrc[j];
    float w = cw[j];
    float4 xv = *(const float4*)(X + (size_t)sn * ldx + (chunk << 2));
    sx += w * xv.x; sy += w * xv.y; sz += w * xv.z; sw += w * xv.w;
  }
  for (int st = C; st < 64; st <<= 1) {
    sx += __shfl_xor(sx, st);
    sy += __shfl_xor(sy, st);
    sz += __shfl_xor(sz, st);
    sw += __shfl_xor(sw, st);
  }
  if (eslot == 0) {
    float vv[4] = {sx, sy, sz, sw};
    int f0 = chunk << 2;
    float v[4];
#pragma unroll
    for (int c = 0; c < 4; c++) {
      int f = f0 + c;
      float u = alpha * vv[c];
      if (add) u += beta * add[(size_t)node * lda + f];
      if (bias && f < Fstore) u += bias[f];
      v[c] = u;
    }
    if (!do_softmax) {
#pragma unroll
      for (int c = 0; c < 4; c++) {
        int f = f0 + c;
        if (f < Fstore) {
          float u = v[c];
          if (relu) u = fmaxf(u, 0.f);
          Y[(size_t)node * ldy + f] = u;
        }
      }
    } else {
      float mx = -INFINITY;
#pragma unroll
      for (int c = 0; c < 4; c++)
        if (f0 + c < Fstore) mx = fmaxf(mx, v[c]);
      mx = fmaxf(mx, __shfl_xor(mx, 1));
      mx = fmaxf(mx, __shfl_xor(mx, 2));
      mx = fmaxf(mx, __shfl_xor(mx, 4));
      float e[4];
      float s = 0.f;
#pragma unroll
      for (int c = 0; c < 4; c++) {
        e[c] = (f0 + c < Fstore) ? __expf(v[c] - mx) : 0.f;
        s += e[c];
      }
      s += __shfl_xor(s, 1);
      s += __shfl_xor(s, 2);
      s += __shfl_xor(s, 4);
      float inv = 1.f / s;
#pragma unroll
      for (int c = 0; c < 4; c++) {
        int f = f0 + c;
        if (f < Fstore) Y[(size_t)node * ldy + f] = e[c] * inv;
      }
    }
  }
}

// ---------------- host orchestration ----------------

static void spmm(hipStream_t s, const int* off, const int* csrc, const float* cw,
                 const float* X, int ldx, float* Y, int ldy,
                 const float* add, int lda, const float* bias,
                 float alpha, float beta, int C_log2, int Fstore, int relu,
                 int do_softmax = 0) {
  spmm_kernel<<<(NN + 3) / 4, 256, 0, s>>>(off, csrc, cw, X, ldx, Y, ldy, add, lda,
                                           bias, alpha, beta, NN, C_log2, Fstore,
                                           relu, do_softmax);
}

extern "C" void kernel_launch(void* const* d_in, const int* in_sizes, int n_in,
                              void* d_out, int out_size, void* d_ws, size_t ws_size,
                              hipStream_t stream) {
  const float* x  = (const float*)d_in[0];
  const int*   ei = (const int*)d_in[1];
  const float* W1 = (const float*)d_in[2];
  const float* b1 = (const float*)d_in[3];
  const float* W2 = (const float*)d_in[4];
  const float* b2 = (const float*)d_in[5];
  const float* W3 = (const float*)d_in[6];
  const float* b3 = (const float*)d_in[7];
  const float* W4 = (const float*)d_in[8];
  const float* b4 = (const float*)d_in[9];
  const float* W5 = (const float*)d_in[10];
  const float* b5 = (const float*)d_in[11];
  float* out = (float*)d_out;
  const int* src = ei;
  const int* dst = ei + NE;
  (void)in_sizes; (void)n_in; (void)out_size; (void)ws_size;

  char* p = (char*)d_ws;
  auto alloc = [&](size_t bytes) {
    char* r = p;
    p += (bytes + 255) & ~(size_t)255;
    return r;
  };
  int*   i_deg  = (int*)alloc(sizeof(int) * NN * 3);  // deg, cnt, pos (one memset)
  int*   i_cnt  = i_deg + NN;
  int*   i_pos  = i_cnt + NN;
  float* f_dinv = (float*)alloc(sizeof(float) * NN);
  int*   i_off  = (int*)alloc(sizeof(int) * (NN + 1));
  int*   i_csrc = (int*)alloc(sizeof(int) * NE);
  float* f_cw   = (float*)alloc(sizeof(float) * NE);
  float* wc1    = (float*)alloc(sizeof(float) * 782 * 48);
  float* wc5    = (float*)alloc(sizeof(float) * 128 * 60);
  float* R1     = (float*)alloc(sizeof(float) * NN * 96);   // ABC1(48)->B3(96)->ABC5(60)
  float* R2     = (float*)alloc(sizeof(float) * NN * 192);  // E1(16)->B4(192)->E5(32)
  float* R3     = (float*)alloc(sizeof(float) * NN * 128);  // B2(48)->H4(128)
  float* P      = (float*)alloc(sizeof(float) * NN * 560);  // k-split partials (max 10x48)

  float* ABC1 = R1;
  float* E1   = R2;
  float* B2   = R3;
  float* B3   = R1;
  float* B4   = R2;
  float* H4   = R3;
  float* ABC5 = R1;
  float* E5   = R2;

  // ---- structure ----
  hipMemsetAsync(i_deg, 0, sizeof(int) * NN * 3, stream);
  deg_kernel<<<(NE + 255) / 256, 256, 0, stream>>>(src, dst, i_deg, i_cnt, NE);
  scan_dinv_kernel<<<1, 1024, 0, stream>>>(i_cnt, i_off, i_deg, f_dinv, NN);
  fill_kernel<<<(NE + 255) / 256, 256, 0, stream>>>(src, dst, f_dinv, i_off, i_pos,
                                                    i_csrc, f_cw, NE);
  wcat2_kernel<<<(782 * 48 + 128 * 60 + 255) / 256, 256, 0, stream>>>(W1, wc1, W5, wc5);

  // ---- Layer 1 (push-through, 782 -> 16): ABC = X @ Wc1 ----
  gemm_v6_kernel<48, 80, false><<<dim3(20, 1, 10), 256, 0, stream>>>(
      x, 782, wc1, 48, P, NN, 782, 80, 48);
  reduce_bias_kernel<<<(NN * 48 + 255) / 256, 256, 0, stream>>>(
      P, ABC1, nullptr, NN, 48, 48, 10, 0);
  // E1 = 2*L(C) + B
  spmm(stream, i_off, i_csrc, f_cw, ABC1 + 32, 48, E1, 16, ABC1 + 16, 48, nullptr,
       2.f, 1.f, 2, 16, 0);
  // H1 = relu(L(E1) + A + b1) -> B2 slot0 (ld 48)
  spmm(stream, i_off, i_csrc, f_cw, E1, 16, B2, 48, ABC1, 48, b1,
       1.f, 1.f, 2, 16, 1);

  // ---- Layer 2 (fused standard, 16 -> 32): concat [T0|T1|T2] in B2 (ld 48) ----
  spmm(stream, i_off, i_csrc, f_cw, B2, 48, B2 + 16, 48, nullptr, 0, nullptr,
       1.f, 0.f, 2, 16, 0);                                           // T1
  spmm(stream, i_off, i_csrc, f_cw, B2 + 16, 48, B2 + 32, 48, B2, 48, nullptr,
       2.f, -1.f, 2, 16, 0);                                          // T2
  gemm_v6_kernel<32, 16, true><<<dim3(20, 1, 3), 256, 0, stream>>>(
      B2, 48, W2, 32, P, NN, 48, 16, 32);
  reduce_bias_kernel<<<(NN * 32 + 255) / 256, 256, 0, stream>>>(
      P, B3, b2, NN, 32, 96, 3, 1);                                   // H2 -> B3 slot0

  // ---- Layer 3 (32 -> 64), concat in B3 (ld 96) ----
  spmm(stream, i_off, i_csrc, f_cw, B3, 96, B3 + 32, 96, nullptr, 0, nullptr,
       1.f, 0.f, 3, 32, 0);
  spmm(stream, i_off, i_csrc, f_cw, B3 + 32, 96, B3 + 64, 96, B3, 96, nullptr,
       2.f, -1.f, 3, 32, 0);
  gemm_v6_kernel<64, 32, true><<<dim3(20, 1, 3), 256, 0, stream>>>(
      B3, 96, W3, 64, P, NN, 96, 32, 64);
  reduce_bias_kernel<<<(NN * 64 + 255) / 256, 256, 0, stream>>>(
      P, B4, b3, NN, 64, 192, 3, 1);                                  // H3 -> B4 slot0

  // ---- Layer 4 (64 -> 128), concat in B4 (ld 192) ----
  spmm(stream, i_off, i_csrc, f_cw, B4, 192, B4 + 64, 192, nullptr, 0, nullptr,
       1.f, 0.f, 4, 64, 0);
  spmm(stream, i_off, i_csrc, f_cw, B4 + 64, 192, B4 + 128, 192, B4, 192, nullptr,
       2.f, -1.f, 4, 64, 0);
  gemm_v6_kernel<64, 48, true><<<dim3(20, 2, 4), 256, 0, stream>>>(
      B4, 192, W4, 128, P, NN, 192, 48, 128);
  reduce_bias_kernel<<<(NN * 128 + 255) / 256, 256, 0, stream>>>(
      P, H4, b4, NN, 128, 128, 4, 1);                                 // H4 (ld 128)

  // ---- Layer 5 (push-through, 128 -> 19 padded 20): ABC = H4 @ Wc5 ----
  gemm_v6_kernel<60, 48, true><<<dim3(20, 1, 3), 256, 0, stream>>>(
      H4, 128, wc5, 60, P, NN, 128, 48, 60);
  reduce_bias_kernel<<<(NN * 60 + 255) / 256, 256, 0, stream>>>(
      P, ABC5, nullptr, NN, 60, 60, 3, 0);
  // E5 = 2*L(C) + B   (C=8 chunks cover 32 cols; cols >= 20 masked at store)
  spmm(stream, i_off, i_csrc, f_cw, ABC5 + 40, 60, E5, 32, ABC5 + 20, 60, nullptr,
       2.f, 1.f, 3, 20, 0);
  // out = softmax(L(E5) + A + b5)  (ld 19, fused)
  spmm(stream, i_off, i_csrc, f_cw, E5, 32, out, 19, ABC5, 60, b5,
       1.f, 1.f, 3, 19, 0, 1);
}

// Round 7
// 368.724 us; speedup vs baseline: 1.1721x; 1.1721x over previous
//
#include <hip/hip_runtime.h>
#include <math.h>

#define NN 10000
#define NE 160000

// ---------------- CSR build ----------------

__global__ __launch_bounds__(256) void deg_kernel(const int* __restrict__ src,
                                                  const int* __restrict__ dst,
                                                  int* __restrict__ deg,
                                                  int* __restrict__ cnt, int E) {
  int e = blockIdx.x * 256 + threadIdx.x;
  if (e < E) {
    atomicAdd(&deg[src[e]], 1);
    atomicAdd(&cnt[dst[e]], 1);
  }
}

// fused: dinv (from deg-by-src) + exclusive scan of cnt (by dst) -> off
__global__ __launch_bounds__(1024) void scan_dinv_kernel(const int* __restrict__ cnt,
                                                         int* __restrict__ off,
                                                         const int* __restrict__ deg,
                                                         float* __restrict__ dinv, int n) {
  __shared__ int sh[1024];
  int t = threadIdx.x;
  for (int i = t; i < n; i += 1024) {
    int d = deg[i];
    dinv[i] = d > 0 ? 1.0f / sqrtf((float)d) : 0.0f;
  }
  int per = (n + 1023) / 1024;
  int base = t * per;
  int sum = 0;
  for (int i = 0; i < per; i++) {
    int idx = base + i;
    if (idx < n) sum += cnt[idx];
  }
  sh[t] = sum;
  __syncthreads();
  for (int d = 1; d < 1024; d <<= 1) {
    int v = (t >= d) ? sh[t - d] : 0;
    __syncthreads();
    if (t >= d) sh[t] += v;
    __syncthreads();
  }
  int run = (t > 0) ? sh[t - 1] : 0;
  for (int i = 0; i < per; i++) {
    int idx = base + i;
    if (idx < n) { off[idx] = run; run += cnt[idx]; }
  }
  if (t == 0) off[n] = sh[1023];
}

__global__ __launch_bounds__(256) void fill_kernel(const int* __restrict__ src,
                                                   const int* __restrict__ dst,
                                                   const float* __restrict__ dinv,
                                                   const int* __restrict__ off,
                                                   int* __restrict__ pos,
                                                   int* __restrict__ csrc,
                                                   float* __restrict__ cw, int E) {
  int e = blockIdx.x * 256 + threadIdx.x;
  if (e < E) {
    int s = src[e], d = dst[e];
    int slot = off[d] + atomicAdd(&pos[d], 1);
    csrc[slot] = s;
    cw[slot] = -dinv[s] * dinv[d];
  }
}

// ---------------- weight concat (both push-through layers, one launch) -------
// Wc [Fin][3*Fp]: cols [0,Fp)=W0-W2, [Fp,2Fp)=W1, [2Fp,3Fp)=W2 ; pad cols zero

__device__ __forceinline__ void wcat_one(const float* __restrict__ W,
                                         float* __restrict__ Wc,
                                         int i, int Fin, int F, int Fp) {
  int w3 = 3 * Fp;
  int row = i / w3;
  int c = i - row * w3;
  int sec = c / Fp;
  int f = c - sec * Fp;
  float v = 0.0f;
  if (f < F) {
    if (sec == 0)      v = W[row * F + f] - W[2 * Fin * F + row * F + f];
    else if (sec == 1) v = W[Fin * F + row * F + f];
    else               v = W[2 * Fin * F + row * F + f];
  }
  Wc[i] = v;
}

__global__ __launch_bounds__(256) void wcat2_kernel(const float* __restrict__ W1,
                                                    float* __restrict__ wc1,
                                                    const float* __restrict__ W5,
                                                    float* __restrict__ wc5) {
  int i = blockIdx.x * 256 + threadIdx.x;
  const int t1 = 782 * 48;
  const int t5 = 128 * 60;
  if (i < t1) {
    wcat_one(W1, wc1, i, 782, 16, 16);
  } else if (i < t1 + t5) {
    wcat_one(W5, wc5, i - t1, 128, 19, 20);
  }
}

// ---------------- GEMM v7: v6 with the VGPR cap REMOVED ---------------------
// v6's __launch_bounds__(256,2) capped VGPR at 128 < the ~180 the kernel needs
// -> scratch spill (62 MB WRITE_SIZE). Occupancy is LDS-limited (56 KB -> 2
// blocks/CU) and waves only halve at VGPR>256, so (256,1) costs nothing and
// lets the prefetch + 96-reg accumulator live in registers.

struct X8 {
  float4 v0, v1, v2, v3, v4, v5, v6, v7;
};

template <bool AL16>
__device__ __forceinline__ float4 ld_row(const float* __restrict__ X, int ldx,
                                         int gr, int M, int kc, int kq4, int kend) {
  float4 v = make_float4(0.f, 0.f, 0.f, 0.f);
  if (gr < M) {
    const float* xp = X + (size_t)gr * ldx + kc + kq4;
    if (kc + 16 <= kend) {
      if (AL16) {
        v = *(const float4*)xp;
      } else {  // rows only 8B-aligned (ldx=782)
        float2 a = *(const float2*)xp;
        float2 b = *(const float2*)(xp + 2);
        v = make_float4(a.x, a.y, b.x, b.y);
      }
    } else {
      int rem = kend - kc;  // 1..15
      if (kq4 + 0 < rem) v.x = xp[0];
      if (kq4 + 1 < rem) v.y = xp[1];
      if (kq4 + 2 < rem) v.z = xp[2];
      if (kq4 + 3 < rem) v.w = xp[3];
    }
  }
  return v;
}

template <bool AL16>
__device__ __forceinline__ X8 load_chunk(const float* __restrict__ X, int ldx,
                                         int row0, int rbase, int M,
                                         int kc, int kq4, int kend) {
  X8 r;
  r.v0 = ld_row<AL16>(X, ldx, row0 + rbase +   0, M, kc, kq4, kend);
  r.v1 = ld_row<AL16>(X, ldx, row0 + rbase +  64, M, kc, kq4, kend);
  r.v2 = ld_row<AL16>(X, ldx, row0 + rbase + 128, M, kc, kq4, kend);
  r.v3 = ld_row<AL16>(X, ldx, row0 + rbase + 192, M, kc, kq4, kend);
  r.v4 = ld_row<AL16>(X, ldx, row0 + rbase + 256, M, kc, kq4, kend);
  r.v5 = ld_row<AL16>(X, ldx, row0 + rbase + 320, M, kc, kq4, kend);
  r.v6 = ld_row<AL16>(X, ldx, row0 + rbase + 384, M, kc, kq4, kend);
  r.v7 = ld_row<AL16>(X, ldx, row0 + rbase + 448, M, kc, kq4, kend);
  return r;
}

template <int TN, int MAXKC, bool AL16>
__global__ __launch_bounds__(256, 1) void gemm_v7_kernel(
    const float* __restrict__ X, int ldx,
    const float* __restrict__ W, int ldw,
    float* __restrict__ P,
    int M, int Kd, int kchunk, int Nd) {
  __shared__ float Xs[512 * 20];
  __shared__ float Ws[MAXKC * TN];
  int t = threadIdx.x;
  int row0 = blockIdx.x * 512;
  int col0 = blockIdx.y * TN;
  int k0 = blockIdx.z * kchunk;
  int kend = k0 + kchunk;
  if (kend > Kd) kend = Kd;
  P += (size_t)blockIdx.z * M * Nd;

  // ---- stage W slice [k0,kend) x TN (zero-filled to MAXKC) ----
  constexpr int W4 = TN / 4;
  for (int idx = t; idx < MAXKC * W4; idx += 256) {
    int wk = idx / W4;
    int wc = (idx - wk * W4) * 4;
    float4 wv = make_float4(0.f, 0.f, 0.f, 0.f);
    if (k0 + wk < kend)
      wv = *(const float4*)(W + (size_t)(k0 + wk) * ldw + col0 + wc);
    *(float4*)(Ws + wk * TN + wc) = wv;
  }

  float acc0[TN], acc1[TN];
#pragma unroll
  for (int c = 0; c < TN; c++) { acc0[c] = 0.f; acc1[c] = 0.f; }

  int rbase = t >> 2;      // 0..63
  int kq4 = (t & 3) << 2;  // 0,4,8,12
  int nchunks = (kend - k0 + 15) >> 4;

  X8 cur = load_chunk<AL16>(X, ldx, row0, rbase, M, k0, kq4, kend);
  for (int ci = 0; ci < nchunks; ci++) {
    X8 nxt = cur;
    if (ci + 1 < nchunks)
      nxt = load_chunk<AL16>(X, ldx, row0, rbase, M, k0 + (ci + 1) * 16, kq4, kend);
    __syncthreads();  // previous compute done (Xs free); Ws ready on ci==0
    {
      float* d0 = Xs + rbase * 20 + kq4;
      *(float4*)(d0 +  0 * 64 * 20) = cur.v0;
      *(float4*)(d0 +  1 * 64 * 20) = cur.v1;
      *(float4*)(d0 +  2 * 64 * 20) = cur.v2;
      *(float4*)(d0 +  3 * 64 * 20) = cur.v3;
      *(float4*)(d0 +  4 * 64 * 20) = cur.v4;
      *(float4*)(d0 +  5 * 64 * 20) = cur.v5;
      *(float4*)(d0 +  6 * 64 * 20) = cur.v6;
      *(float4*)(d0 +  7 * 64 * 20) = cur.v7;
    }
    __syncthreads();  // Xs visible
    int kb = ci << 4;
#pragma unroll
    for (int kg = 0; kg < 4; kg++) {
      float4 xa = *(const float4*)(Xs + t * 20 + (kg << 2));
      float4 xb = *(const float4*)(Xs + (t + 256) * 20 + (kg << 2));
      float xs0[4] = {xa.x, xa.y, xa.z, xa.w};
      float xs1[4] = {xb.x, xb.y, xb.z, xb.w};
#pragma unroll
      for (int j = 0; j < 4; j++) {
        const float* wr = Ws + (kb + (kg << 2) + j) * TN;
#pragma unroll
        for (int c = 0; c < TN; c += 4) {
          float4 wv = *(const float4*)(wr + c);  // wave-uniform -> broadcast
          acc0[c + 0] += xs0[j] * wv.x; acc0[c + 1] += xs0[j] * wv.y;
          acc0[c + 2] += xs0[j] * wv.z; acc0[c + 3] += xs0[j] * wv.w;
          acc1[c + 0] += xs1[j] * wv.x; acc1[c + 1] += xs1[j] * wv.y;
          acc1[c + 2] += xs1[j] * wv.z; acc1[c + 3] += xs1[j] * wv.w;
        }
      }
    }
    cur = nxt;
  }

  // ---- store partials (explicit, no pointer-select over acc arrays) ----
  {
    int r = row0 + t;
    if (r < M) {
      float* pr = P + (size_t)r * Nd + col0;
#pragma unroll
      for (int c = 0; c < TN; c += 4)
        *(float4*)(pr + c) = make_float4(acc0[c], acc0[c + 1], acc0[c + 2], acc0[c + 3]);
    }
  }
  {
    int r = row0 + t + 256;
    if (r < M) {
      float* pr = P + (size_t)r * Nd + col0;
#pragma unroll
      for (int c = 0; c < TN; c += 4)
        *(float4*)(pr + c) = make_float4(acc1[c], acc1[c + 1], acc1[c + 2], acc1[c + 3]);
    }
  }
}

// fused k-split reduce + bias + relu: Y[r*ldy+c] = act(sum_j P[j][r*Nd+c] + bias[c])
__global__ __launch_bounds__(256) void reduce_bias_kernel(
    const float* __restrict__ P, float* __restrict__ Y,
    const float* __restrict__ bias,
    int M, int Nd, int ldy, int nsplit, int relu) {
  int i = blockIdx.x * 256 + threadIdx.x;
  int total = M * Nd;
  if (i >= total) return;
  float s = 0.f;
  for (int j = 0; j < nsplit; j++) s += P[(size_t)j * total + i];
  int r = i / Nd, c = i - r * Nd;
  if (bias) s += bias[c];
  if (relu) s = fmaxf(s, 0.f);
  Y[(size_t)r * ldy + c] = s;
}

// ---------------- SpMM: wave-per-node (optionally fused softmax) ------------

__global__ __launch_bounds__(256) void spmm_kernel(
    const int* __restrict__ off,
    const int* __restrict__ csrc,
    const float* __restrict__ cw,
    const float* __restrict__ X, int ldx,
    float* __restrict__ Y, int ldy,
    const float* __restrict__ add, int lda,
    const float* __restrict__ bias,
    float alpha, float beta,
    int n, int C_log2, int Fstore, int relu, int do_softmax) {
  int wave_in_blk = threadIdx.x >> 6;
  int lane = threadIdx.x & 63;
  int node = blockIdx.x * 4 + wave_in_blk;
  if (node >= n) return;
  int C = 1 << C_log2;
  int chunk = lane & (C - 1);
  int eslot = lane >> C_log2;
  int Epar = 64 >> C_log2;

  int j0 = off[node], j1 = off[node + 1];
  float sx = 0.f, sy = 0.f, sz = 0.f, sw = 0.f;
  for (int j = j0 + eslot; j < j1; j += Epar) {
    int sn = csrc[j];
    float w = cw[j];
    float4 xv = *(const float4*)(X + (size_t)sn * ldx + (chunk << 2));
    sx += w * xv.x; sy += w * xv.y; sz += w * xv.z; sw += w * xv.w;
  }
  for (int st = C; st < 64; st <<= 1) {
    sx += __shfl_xor(sx, st);
    sy += __shfl_xor(sy, st);
    sz += __shfl_xor(sz, st);
    sw += __shfl_xor(sw, st);
  }
  if (eslot == 0) {
    float vv[4] = {sx, sy, sz, sw};
    int f0 = chunk << 2;
    float v[4];
#pragma unroll
    for (int c = 0; c < 4; c++) {
      int f = f0 + c;
      float u = alpha * vv[c];
      if (add) u += beta * add[(size_t)node * lda + f];
      if (bias && f < Fstore) u += bias[f];
      v[c] = u;
    }
    if (!do_softmax) {
#pragma unroll
      for (int c = 0; c < 4; c++) {
        int f = f0 + c;
        if (f < Fstore) {
          float u = v[c];
          if (relu) u = fmaxf(u, 0.f);
          Y[(size_t)node * ldy + f] = u;
        }
      }
    } else {
      float mx = -INFINITY;
#pragma unroll
      for (int c = 0; c < 4; c++)
        if (f0 + c < Fstore) mx = fmaxf(mx, v[c]);
      mx = fmaxf(mx, __shfl_xor(mx, 1));
      mx = fmaxf(mx, __shfl_xor(mx, 2));
      mx = fmaxf(mx, __shfl_xor(mx, 4));
      float e[4];
      float s = 0.f;
#pragma unroll
      for (int c = 0; c < 4; c++) {
        e[c] = (f0 + c < Fstore) ? __expf(v[c] - mx) : 0.f;
        s += e[c];
      }
      s += __shfl_xor(s, 1);
      s += __shfl_xor(s, 2);
      s += __shfl_xor(s, 4);
      float inv = 1.f / s;
#pragma unroll
      for (int c = 0; c < 4; c++) {
        int f = f0 + c;
        if (f < Fstore) Y[(size_t)node * ldy + f] = e[c] * inv;
      }
    }
  }
}

// ---------------- host orchestration ----------------

static void spmm(hipStream_t s, const int* off, const int* csrc, const float* cw,
                 const float* X, int ldx, float* Y, int ldy,
                 const float* add, int lda, const float* bias,
                 float alpha, float beta, int C_log2, int Fstore, int relu,
                 int do_softmax = 0) {
  spmm_kernel<<<(NN + 3) / 4, 256, 0, s>>>(off, csrc, cw, X, ldx, Y, ldy, add, lda,
                                           bias, alpha, beta, NN, C_log2, Fstore,
                                           relu, do_softmax);
}

extern "C" void kernel_launch(void* const* d_in, const int* in_sizes, int n_in,
                              void* d_out, int out_size, void* d_ws, size_t ws_size,
                              hipStream_t stream) {
  const float* x  = (const float*)d_in[0];
  const int*   ei = (const int*)d_in[1];
  const float* W1 = (const float*)d_in[2];
  const float* b1 = (const float*)d_in[3];
  const float* W2 = (const float*)d_in[4];
  const float* b2 = (const float*)d_in[5];
  const float* W3 = (const float*)d_in[6];
  const float* b3 = (const float*)d_in[7];
  const float* W4 = (const float*)d_in[8];
  const float* b4 = (const float*)d_in[9];
  const float* W5 = (const float*)d_in[10];
  const float* b5 = (const float*)d_in[11];
  float* out = (float*)d_out;
  const int* src = ei;
  const int* dst = ei + NE;
  (void)in_sizes; (void)n_in; (void)out_size; (void)ws_size;

  char* p = (char*)d_ws;
  auto alloc = [&](size_t bytes) {
    char* r = p;
    p += (bytes + 255) & ~(size_t)255;
    return r;
  };
  int*   i_deg  = (int*)alloc(sizeof(int) * NN * 3);  // deg, cnt, pos (one memset)
  int*   i_cnt  = i_deg + NN;
  int*   i_pos  = i_cnt + NN;
  float* f_dinv = (float*)alloc(sizeof(float) * NN);
  int*   i_off  = (int*)alloc(sizeof(int) * (NN + 1));
  int*   i_csrc = (int*)alloc(sizeof(int) * NE);
  float* f_cw   = (float*)alloc(sizeof(float) * NE);
  float* wc1    = (float*)alloc(sizeof(float) * 782 * 48);
  float* wc5    = (float*)alloc(sizeof(float) * 128 * 60);
  float* R1     = (float*)alloc(sizeof(float) * NN * 96);   // ABC1(48)->B3(96)->ABC5(60)
  float* R2     = (float*)alloc(sizeof(float) * NN * 192);  // E1(16)->B4(192)->E5(32)
  float* R3     = (float*)alloc(sizeof(float) * NN * 128);  // B2(48)->H4(128)
  float* P      = (float*)alloc(sizeof(float) * NN * 560);  // k-split partials (max 10x48)

  float* ABC1 = R1;
  float* E1   = R2;
  float* B2   = R3;
  float* B3   = R1;
  float* B4   = R2;
  float* H4   = R3;
  float* ABC5 = R1;
  float* E5   = R2;

  // ---- structure ----
  hipMemsetAsync(i_deg, 0, sizeof(int) * NN * 3, stream);
  deg_kernel<<<(NE + 255) / 256, 256, 0, stream>>>(src, dst, i_deg, i_cnt, NE);
  scan_dinv_kernel<<<1, 1024, 0, stream>>>(i_cnt, i_off, i_deg, f_dinv, NN);
  fill_kernel<<<(NE + 255) / 256, 256, 0, stream>>>(src, dst, f_dinv, i_off, i_pos,
                                                    i_csrc, f_cw, NE);
  wcat2_kernel<<<(782 * 48 + 128 * 60 + 255) / 256, 256, 0, stream>>>(W1, wc1, W5, wc5);

  // ---- Layer 1 (push-through, 782 -> 16): ABC = X @ Wc1 ----
  gemm_v7_kernel<48, 80, false><<<dim3(20, 1, 10), 256, 0, stream>>>(
      x, 782, wc1, 48, P, NN, 782, 80, 48);
  reduce_bias_kernel<<<(NN * 48 + 255) / 256, 256, 0, stream>>>(
      P, ABC1, nullptr, NN, 48, 48, 10, 0);
  // E1 = 2*L(C) + B
  spmm(stream, i_off, i_csrc, f_cw, ABC1 + 32, 48, E1, 16, ABC1 + 16, 48, nullptr,
       2.f, 1.f, 2, 16, 0);
  // H1 = relu(L(E1) + A + b1) -> B2 slot0 (ld 48)
  spmm(stream, i_off, i_csrc, f_cw, E1, 16, B2, 48, ABC1, 48, b1,
       1.f, 1.f, 2, 16, 1);

  // ---- Layer 2 (fused standard, 16 -> 32): concat [T0|T1|T2] in B2 (ld 48) ----
  spmm(stream, i_off, i_csrc, f_cw, B2, 48, B2 + 16, 48, nullptr, 0, nullptr,
       1.f, 0.f, 2, 16, 0);                                           // T1
  spmm(stream, i_off, i_csrc, f_cw, B2 + 16, 48, B2 + 32, 48, B2, 48, nullptr,
       2.f, -1.f, 2, 16, 0);                                          // T2
  gemm_v7_kernel<32, 16, true><<<dim3(20, 1, 3), 256, 0, stream>>>(
      B2, 48, W2, 32, P, NN, 48, 16, 32);
  reduce_bias_kernel<<<(NN * 32 + 255) / 256, 256, 0, stream>>>(
      P, B3, b2, NN, 32, 96, 3, 1);                                   // H2 -> B3 slot0

  // ---- Layer 3 (32 -> 64), concat in B3 (ld 96) ----
  spmm(stream, i_off, i_csrc, f_cw, B3, 96, B3 + 32, 96, nullptr, 0, nullptr,
       1.f, 0.f, 3, 32, 0);
  spmm(stream, i_off, i_csrc, f_cw, B3 + 32, 96, B3 + 64, 96, B3, 96, nullptr,
       2.f, -1.f, 3, 32, 0);
  gemm_v7_kernel<64, 32, true><<<dim3(20, 1, 3), 256, 0, stream>>>(
      B3, 96, W3, 64, P, NN, 96, 32, 64);
  reduce_bias_kernel<<<(NN * 64 + 255) / 256, 256, 0, stream>>>(
      P, B4, b3, NN, 64, 192, 3, 1);                                  // H3 -> B4 slot0

  // ---- Layer 4 (64 -> 128), concat in B4 (ld 192) ----
  spmm(stream, i_off, i_csrc, f_cw, B4, 192, B4 + 64, 192, nullptr, 0, nullptr,
       1.f, 0.f, 4, 64, 0);
  spmm(stream, i_off, i_csrc, f_cw, B4 + 64, 192, B4 + 128, 192, B4, 192, nullptr,
       2.f, -1.f, 4, 64, 0);
  gemm_v7_kernel<64, 48, true><<<dim3(20, 2, 4), 256, 0, stream>>>(
      B4, 192, W4, 128, P, NN, 192, 48, 128);
  reduce_bias_kernel<<<(NN * 128 + 255) / 256, 256, 0, stream>>>(
      P, H4, b4, NN, 128, 128, 4, 1);                                 // H4 (ld 128)

  // ---- Layer 5 (push-through, 128 -> 19 padded 20): ABC = H4 @ Wc5 ----
  gemm_v7_kernel<60, 48, true><<<dim3(20, 1, 3), 256, 0, stream>>>(
      H4, 128, wc5, 60, P, NN, 128, 48, 60);
  reduce_bias_kernel<<<(NN * 60 + 255) / 256, 256, 0, stream>>>(
      P, ABC5, nullptr, NN, 60, 60, 3, 0);
  // E5 = 2*L(C) + B   (C=8 chunks cover 32 cols; cols >= 20 masked at store)
  spmm(stream, i_off, i_csrc, f_cw, ABC5 + 40, 60, E5, 32, ABC5 + 20, 60, nullptr,
       2.f, 1.f, 3, 20, 0);
  // out = softmax(L(E5) + A + b5)  (ld 19, fused)
  spmm(stream, i_off, i_csrc, f_cw, E5, 32, out, 19, ABC5, 60, b5,
       1.f, 1.f, 3, 19, 0, 1);
}

// Round 8
// 345.659 us; speedup vs baseline: 1.2503x; 1.0667x over previous
//
#include <hip/hip_runtime.h>
#include <math.h>

#define NN 10000
#define NE 160000

// ---------------- CSR build ----------------

__global__ __launch_bounds__(256) void deg_kernel(const int* __restrict__ src,
                                                  const int* __restrict__ dst,
                                                  int* __restrict__ deg,
                                                  int* __restrict__ cnt, int E) {
  int e = blockIdx.x * 256 + threadIdx.x;
  if (e < E) {
    atomicAdd(&deg[src[e]], 1);
    atomicAdd(&cnt[dst[e]], 1);
  }
}

// fused: dinv (from deg-by-src) + exclusive scan of cnt (by dst) -> off
__global__ __launch_bounds__(1024) void scan_dinv_kernel(const int* __restrict__ cnt,
                                                         int* __restrict__ off,
                                                         const int* __restrict__ deg,
                                                         float* __restrict__ dinv, int n) {
  __shared__ int sh[1024];
  int t = threadIdx.x;
  for (int i = t; i < n; i += 1024) {
    int d = deg[i];
    dinv[i] = d > 0 ? 1.0f / sqrtf((float)d) : 0.0f;
  }
  int per = (n + 1023) / 1024;
  int base = t * per;
  int sum = 0;
  for (int i = 0; i < per; i++) {
    int idx = base + i;
    if (idx < n) sum += cnt[idx];
  }
  sh[t] = sum;
  __syncthreads();
  for (int d = 1; d < 1024; d <<= 1) {
    int v = (t >= d) ? sh[t - d] : 0;
    __syncthreads();
    if (t >= d) sh[t] += v;
    __syncthreads();
  }
  int run = (t > 0) ? sh[t - 1] : 0;
  for (int i = 0; i < per; i++) {
    int idx = base + i;
    if (idx < n) { off[idx] = run; run += cnt[idx]; }
  }
  if (t == 0) off[n] = sh[1023];
}

__global__ __launch_bounds__(256) void fill_kernel(const int* __restrict__ src,
                                                   const int* __restrict__ dst,
                                                   const float* __restrict__ dinv,
                                                   const int* __restrict__ off,
                                                   int* __restrict__ pos,
                                                   int* __restrict__ csrc,
                                                   float* __restrict__ cw, int E) {
  int e = blockIdx.x * 256 + threadIdx.x;
  if (e < E) {
    int s = src[e], d = dst[e];
    int slot = off[d] + atomicAdd(&pos[d], 1);
    csrc[slot] = s;
    cw[slot] = -dinv[s] * dinv[d];
  }
}

// ---------------- weight concat (both push-through layers, one launch) -------
// Wc [Fin][3*Fp]: cols [0,Fp)=W0-W2, [Fp,2Fp)=W1, [2Fp,3Fp)=W2 ; pad cols zero

__device__ __forceinline__ void wcat_one(const float* __restrict__ W,
                                         float* __restrict__ Wc,
                                         int i, int Fin, int F, int Fp) {
  int w3 = 3 * Fp;
  int row = i / w3;
  int c = i - row * w3;
  int sec = c / Fp;
  int f = c - sec * Fp;
  float v = 0.0f;
  if (f < F) {
    if (sec == 0)      v = W[row * F + f] - W[2 * Fin * F + row * F + f];
    else if (sec == 1) v = W[Fin * F + row * F + f];
    else               v = W[2 * Fin * F + row * F + f];
  }
  Wc[i] = v;
}

__global__ __launch_bounds__(256) void wcat2_kernel(const float* __restrict__ W1,
                                                    float* __restrict__ wc1,
                                                    const float* __restrict__ W5,
                                                    float* __restrict__ wc5) {
  int i = blockIdx.x * 256 + threadIdx.x;
  const int t1 = 782 * 48;
  const int t5 = 128 * 60;
  if (i < t1) {
    wcat_one(W1, wc1, i, 782, 16, 16);
  } else if (i < t1 + t5) {
    wcat_one(W5, wc5, i - t1, 128, 19, 20);
  }
}

// ---------------- GEMM v8: no X-LDS round-trip, no K-loop barriers ----------
// 128 threads/block; thread t owns rows {t, t+128, t+256, t+384} (512/block).
// X k-slices (8 floats/row) load straight into registers, double-buffered; W
// kchunk-slice staged to LDS once per block (one barrier), read as wave-
// uniform b128 broadcasts amortized over 4 rows. K-loop has zero
// __syncthreads -> no vmcnt(0) barrier drain; per chunk: issue next loads,
// ~8*4*TN*2 cyc of FMA hides them. Partials to P[z][M*Nd].

struct Row8 { float4 lo, hi; };  // 8 consecutive k-floats of one row

template <bool AL16>
__device__ __forceinline__ Row8 ld_row8(const float* __restrict__ X, int ldx,
                                        int gr, int M, int kc, int kend) {
  Row8 r;
  r.lo = make_float4(0.f, 0.f, 0.f, 0.f);
  r.hi = make_float4(0.f, 0.f, 0.f, 0.f);
  if (gr < M && kc < kend) {
    const float* xp = X + (size_t)gr * ldx + kc;
    if (kc + 8 <= kend) {
      if (AL16) {
        r.lo = ((const float4*)xp)[0];
        r.hi = ((const float4*)xp)[1];
      } else {  // rows only 8B-aligned (ldx=782, kc even)
        float2 a = *(const float2*)xp;
        float2 b = *(const float2*)(xp + 2);
        float2 c = *(const float2*)(xp + 4);
        float2 d = *(const float2*)(xp + 6);
        r.lo = make_float4(a.x, a.y, b.x, b.y);
        r.hi = make_float4(c.x, c.y, d.x, d.y);
      }
    } else {
      int rem = kend - kc;  // 1..7
      r.lo.x = xp[0];
      if (rem > 1) r.lo.y = xp[1];
      if (rem > 2) r.lo.z = xp[2];
      if (rem > 3) r.lo.w = xp[3];
      if (rem > 4) r.hi.x = xp[4];
      if (rem > 5) r.hi.y = xp[5];
      if (rem > 6) r.hi.z = xp[6];
    }
  }
  return r;
}

struct X4R { Row8 r0, r1, r2, r3; };  // 4 rows' 8-float slices

template <bool AL16>
__device__ __forceinline__ X4R ld_chunk4(const float* __restrict__ X, int ldx,
                                         int row0, int t, int M, int kc, int kend) {
  X4R x;
  x.r0 = ld_row8<AL16>(X, ldx, row0 + t,       M, kc, kend);
  x.r1 = ld_row8<AL16>(X, ldx, row0 + t + 128, M, kc, kend);
  x.r2 = ld_row8<AL16>(X, ldx, row0 + t + 256, M, kc, kend);
  x.r3 = ld_row8<AL16>(X, ldx, row0 + t + 384, M, kc, kend);
  return x;
}

__device__ __forceinline__ float comp8(const Row8& r, int k) {  // k compile-time
  switch (k) {
    case 0: return r.lo.x; case 1: return r.lo.y;
    case 2: return r.lo.z; case 3: return r.lo.w;
    case 4: return r.hi.x; case 5: return r.hi.y;
    case 6: return r.hi.z; default: return r.hi.w;
  }
}

template <int TN, int MAXKC, bool AL16>
__global__ __launch_bounds__(128, 1) void gemm_v8_kernel(
    const float* __restrict__ X, int ldx,
    const float* __restrict__ W, int ldw,
    float* __restrict__ P,
    int M, int Kd, int kchunk, int Nd) {
  __shared__ float Ws[MAXKC * TN];
  int t = threadIdx.x;  // 0..127
  int row0 = blockIdx.x * 512;
  int col0 = blockIdx.y * TN;
  int k0 = blockIdx.z * kchunk;
  int kend = k0 + kchunk;
  if (kend > Kd) kend = Kd;
  P += (size_t)blockIdx.z * M * Nd;

  // ---- stage W slice [k0,kend) x TN once (zero-filled to MAXKC) ----
  constexpr int W4 = TN / 4;
  for (int idx = t; idx < MAXKC * W4; idx += 128) {
    int wk = idx / W4;
    int wc = (idx - wk * W4) * 4;
    float4 wv = make_float4(0.f, 0.f, 0.f, 0.f);
    if (k0 + wk < kend)
      wv = *(const float4*)(W + (size_t)(k0 + wk) * ldw + col0 + wc);
    *(float4*)(Ws + wk * TN + wc) = wv;
  }
  __syncthreads();  // the only barrier

  float acc0[TN], acc1[TN], acc2[TN], acc3[TN];
#pragma unroll
  for (int c = 0; c < TN; c++) { acc0[c] = 0.f; acc1[c] = 0.f; acc2[c] = 0.f; acc3[c] = 0.f; }

  int nchunks = (kend - k0 + 7) >> 3;
  X4R cur = ld_chunk4<AL16>(X, ldx, row0, t, M, k0, kend);
  for (int ci = 0; ci < nchunks; ci++) {
    X4R nxt = cur;
    if (ci + 1 < nchunks)
      nxt = ld_chunk4<AL16>(X, ldx, row0, t, M, k0 + (ci + 1) * 8, kend);
    int kb = ci << 3;
#pragma unroll
    for (int k = 0; k < 8; k++) {
      float x0 = comp8(cur.r0, k);
      float x1 = comp8(cur.r1, k);
      float x2 = comp8(cur.r2, k);
      float x3 = comp8(cur.r3, k);
      const float* wr = Ws + (kb + k) * TN;
#pragma unroll
      for (int c = 0; c < TN; c += 4) {
        float4 wv = *(const float4*)(wr + c);  // wave-uniform -> LDS broadcast
        acc0[c + 0] += x0 * wv.x; acc0[c + 1] += x0 * wv.y;
        acc0[c + 2] += x0 * wv.z; acc0[c + 3] += x0 * wv.w;
        acc1[c + 0] += x1 * wv.x; acc1[c + 1] += x1 * wv.y;
        acc1[c + 2] += x1 * wv.z; acc1[c + 3] += x1 * wv.w;
        acc2[c + 0] += x2 * wv.x; acc2[c + 1] += x2 * wv.y;
        acc2[c + 2] += x2 * wv.z; acc2[c + 3] += x2 * wv.w;
        acc3[c + 0] += x3 * wv.x; acc3[c + 1] += x3 * wv.y;
        acc3[c + 2] += x3 * wv.z; acc3[c + 3] += x3 * wv.w;
      }
    }
    cur = nxt;
  }

  // ---- store partials (explicit per-row blocks) ----
  {
    int r = row0 + t;
    if (r < M) {
      float* pr = P + (size_t)r * Nd + col0;
#pragma unroll
      for (int c = 0; c < TN; c += 4)
        *(float4*)(pr + c) = make_float4(acc0[c], acc0[c + 1], acc0[c + 2], acc0[c + 3]);
    }
  }
  {
    int r = row0 + t + 128;
    if (r < M) {
      float* pr = P + (size_t)r * Nd + col0;
#pragma unroll
      for (int c = 0; c < TN; c += 4)
        *(float4*)(pr + c) = make_float4(acc1[c], acc1[c + 1], acc1[c + 2], acc1[c + 3]);
    }
  }
  {
    int r = row0 + t + 256;
    if (r < M) {
      float* pr = P + (size_t)r * Nd + col0;
#pragma unroll
      for (int c = 0; c < TN; c += 4)
        *(float4*)(pr + c) = make_float4(acc2[c], acc2[c + 1], acc2[c + 2], acc2[c + 3]);
    }
  }
  {
    int r = row0 + t + 384;
    if (r < M) {
      float* pr = P + (size_t)r * Nd + col0;
#pragma unroll
      for (int c = 0; c < TN; c += 4)
        *(float4*)(pr + c) = make_float4(acc3[c], acc3[c + 1], acc3[c + 2], acc3[c + 3]);
    }
  }
}

// fused k-split reduce + bias + relu: Y[r*ldy+c] = act(sum_j P[j][r*Nd+c] + bias[c])
__global__ __launch_bounds__(256) void reduce_bias_kernel(
    const float* __restrict__ P, float* __restrict__ Y,
    const float* __restrict__ bias,
    int M, int Nd, int ldy, int nsplit, int relu) {
  int i = blockIdx.x * 256 + threadIdx.x;
  int total = M * Nd;
  if (i >= total) return;
  float s = 0.f;
  for (int j = 0; j < nsplit; j++) s += P[(size_t)j * total + i];
  int r = i / Nd, c = i - r * Nd;
  if (bias) s += bias[c];
  if (relu) s = fmaxf(s, 0.f);
  Y[(size_t)r * ldy + c] = s;
}

// ---------------- SpMM: wave-per-node (optionally fused softmax) ------------

__global__ __launch_bounds__(256) void spmm_kernel(
    const int* __restrict__ off,
    const int* __restrict__ csrc,
    const float* __restrict__ cw,
    const float* __restrict__ X, int ldx,
    float* __restrict__ Y, int ldy,
    const float* __restrict__ add, int lda,
    const float* __restrict__ bias,
    float alpha, float beta,
    int n, int C_log2, int Fstore, int relu, int do_softmax) {
  int wave_in_blk = threadIdx.x >> 6;
  int lane = threadIdx.x & 63;
  int node = blockIdx.x * 4 + wave_in_blk;
  if (node >= n) return;
  int C = 1 << C_log2;
  int chunk = lane & (C - 1);
  int eslot = lane >> C_log2;
  int Epar = 64 >> C_log2;

  int j0 = off[node], j1 = off[node + 1];
  float sx = 0.f, sy = 0.f, sz = 0.f, sw = 0.f;
  for (int j = j0 + eslot; j < j1; j += Epar) {
    int sn = csrc[j];
    float w = cw[j];
    float4 xv = *(const float4*)(X + (size_t)sn * ldx + (chunk << 2));
    sx += w * xv.x; sy += w * xv.y; sz += w * xv.z; sw += w * xv.w;
  }
  for (int st = C; st < 64; st <<= 1) {
    sx += __shfl_xor(sx, st);
    sy += __shfl_xor(sy, st);
    sz += __shfl_xor(sz, st);
    sw += __shfl_xor(sw, st);
  }
  if (eslot == 0) {
    float vv[4] = {sx, sy, sz, sw};
    int f0 = chunk << 2;
    float v[4];
#pragma unroll
    for (int c = 0; c < 4; c++) {
      int f = f0 + c;
      float u = alpha * vv[c];
      if (add) u += beta * add[(size_t)node * lda + f];
      if (bias && f < Fstore) u += bias[f];
      v[c] = u;
    }
    if (!do_softmax) {
#pragma unroll
      for (int c = 0; c < 4; c++) {
        int f = f0 + c;
        if (f < Fstore) {
          float u = v[c];
          if (relu) u = fmaxf(u, 0.f);
          Y[(size_t)node * ldy + f] = u;
        }
      }
    } else {
      float mx = -INFINITY;
#pragma unroll
      for (int c = 0; c < 4; c++)
        if (f0 + c < Fstore) mx = fmaxf(mx, v[c]);
      mx = fmaxf(mx, __shfl_xor(mx, 1));
      mx = fmaxf(mx, __shfl_xor(mx, 2));
      mx = fmaxf(mx, __shfl_xor(mx, 4));
      float e[4];
      float s = 0.f;
#pragma unroll
      for (int c = 0; c < 4; c++) {
        e[c] = (f0 + c < Fstore) ? __expf(v[c] - mx) : 0.f;
        s += e[c];
      }
      s += __shfl_xor(s, 1);
      s += __shfl_xor(s, 2);
      s += __shfl_xor(s, 4);
      float inv = 1.f / s;
#pragma unroll
      for (int c = 0; c < 4; c++) {
        int f = f0 + c;
        if (f < Fstore) Y[(size_t)node * ldy + f] = e[c] * inv;
      }
    }
  }
}

// ---------------- host orchestration ----------------

static void spmm(hipStream_t s, const int* off, const int* csrc, const float* cw,
                 const float* X, int ldx, float* Y, int ldy,
                 const float* add, int lda, const float* bias,
                 float alpha, float beta, int C_log2, int Fstore, int relu,
                 int do_softmax = 0) {
  spmm_kernel<<<(NN + 3) / 4, 256, 0, s>>>(off, csrc, cw, X, ldx, Y, ldy, add, lda,
                                           bias, alpha, beta, NN, C_log2, Fstore,
                                           relu, do_softmax);
}

extern "C" void kernel_launch(void* const* d_in, const int* in_sizes, int n_in,
                              void* d_out, int out_size, void* d_ws, size_t ws_size,
                              hipStream_t stream) {
  const float* x  = (const float*)d_in[0];
  const int*   ei = (const int*)d_in[1];
  const float* W1 = (const float*)d_in[2];
  const float* b1 = (const float*)d_in[3];
  const float* W2 = (const float*)d_in[4];
  const float* b2 = (const float*)d_in[5];
  const float* W3 = (const float*)d_in[6];
  const float* b3 = (const float*)d_in[7];
  const float* W4 = (const float*)d_in[8];
  const float* b4 = (const float*)d_in[9];
  const float* W5 = (const float*)d_in[10];
  const float* b5 = (const float*)d_in[11];
  float* out = (float*)d_out;
  const int* src = ei;
  const int* dst = ei + NE;
  (void)in_sizes; (void)n_in; (void)out_size; (void)ws_size;

  char* p = (char*)d_ws;
  auto alloc = [&](size_t bytes) {
    char* r = p;
    p += (bytes + 255) & ~(size_t)255;
    return r;
  };
  int*   i_deg  = (int*)alloc(sizeof(int) * NN * 3);  // deg, cnt, pos (one memset)
  int*   i_cnt  = i_deg + NN;
  int*   i_pos  = i_cnt + NN;
  float* f_dinv = (float*)alloc(sizeof(float) * NN);
  int*   i_off  = (int*)alloc(sizeof(int) * (NN + 1));
  int*   i_csrc = (int*)alloc(sizeof(int) * NE);
  float* f_cw   = (float*)alloc(sizeof(float) * NE);
  float* wc1    = (float*)alloc(sizeof(float) * 782 * 48);
  float* wc5    = (float*)alloc(sizeof(float) * 128 * 60);
  float* R1     = (float*)alloc(sizeof(float) * NN * 96);   // ABC1(48)->B3(96)->ABC5(60)
  float* R2     = (float*)alloc(sizeof(float) * NN * 192);  // E1(16)->B4(192)->E5(32)
  float* R3     = (float*)alloc(sizeof(float) * NN * 128);  // B2(48)->H4(128)
  float* P      = (float*)alloc(sizeof(float) * NN * 640);  // k-split partials (max 13x48)

  float* ABC1 = R1;
  float* E1   = R2;
  float* B2   = R3;
  float* B3   = R1;
  float* B4   = R2;
  float* H4   = R3;
  float* ABC5 = R1;
  float* E5   = R2;

  // ---- structure ----
  hipMemsetAsync(i_deg, 0, sizeof(int) * NN * 3, stream);
  deg_kernel<<<(NE + 255) / 256, 256, 0, stream>>>(src, dst, i_deg, i_cnt, NE);
  scan_dinv_kernel<<<1, 1024, 0, stream>>>(i_cnt, i_off, i_deg, f_dinv, NN);
  fill_kernel<<<(NE + 255) / 256, 256, 0, stream>>>(src, dst, f_dinv, i_off, i_pos,
                                                    i_csrc, f_cw, NE);
  wcat2_kernel<<<(782 * 48 + 128 * 60 + 255) / 256, 256, 0, stream>>>(W1, wc1, W5, wc5);

  // ---- Layer 1 (push-through, 782 -> 16): ABC = X @ Wc1 ----
  gemm_v8_kernel<24, 64, false><<<dim3(20, 2, 13), 128, 0, stream>>>(
      x, 782, wc1, 48, P, NN, 782, 64, 48);
  reduce_bias_kernel<<<(NN * 48 + 255) / 256, 256, 0, stream>>>(
      P, ABC1, nullptr, NN, 48, 48, 13, 0);
  // E1 = 2*L(C) + B
  spmm(stream, i_off, i_csrc, f_cw, ABC1 + 32, 48, E1, 16, ABC1 + 16, 48, nullptr,
       2.f, 1.f, 2, 16, 0);
  // H1 = relu(L(E1) + A + b1) -> B2 slot0 (ld 48)
  spmm(stream, i_off, i_csrc, f_cw, E1, 16, B2, 48, ABC1, 48, b1,
       1.f, 1.f, 2, 16, 1);

  // ---- Layer 2 (fused standard, 16 -> 32): concat [T0|T1|T2] in B2 (ld 48) ----
  spmm(stream, i_off, i_csrc, f_cw, B2, 48, B2 + 16, 48, nullptr, 0, nullptr,
       1.f, 0.f, 2, 16, 0);                                           // T1
  spmm(stream, i_off, i_csrc, f_cw, B2 + 16, 48, B2 + 32, 48, B2, 48, nullptr,
       2.f, -1.f, 2, 16, 0);                                          // T2
  gemm_v8_kernel<16, 16, true><<<dim3(20, 2, 3), 128, 0, stream>>>(
      B2, 48, W2, 32, P, NN, 48, 16, 32);
  reduce_bias_kernel<<<(NN * 32 + 255) / 256, 256, 0, stream>>>(
      P, B3, b2, NN, 32, 96, 3, 1);                                   // H2 -> B3 slot0

  // ---- Layer 3 (32 -> 64), concat in B3 (ld 96) ----
  spmm(stream, i_off, i_csrc, f_cw, B3, 96, B3 + 32, 96, nullptr, 0, nullptr,
       1.f, 0.f, 3, 32, 0);
  spmm(stream, i_off, i_csrc, f_cw, B3 + 32, 96, B3 + 64, 96, B3, 96, nullptr,
       2.f, -1.f, 3, 32, 0);
  gemm_v8_kernel<32, 32, true><<<dim3(20, 2, 3), 128, 0, stream>>>(
      B3, 96, W3, 64, P, NN, 96, 32, 64);
  reduce_bias_kernel<<<(NN * 64 + 255) / 256, 256, 0, stream>>>(
      P, B4, b3, NN, 64, 192, 3, 1);                                  // H3 -> B4 slot0

  // ---- Layer 4 (64 -> 128), concat in B4 (ld 192) ----
  spmm(stream, i_off, i_csrc, f_cw, B4, 192, B4 + 64, 192, nullptr, 0, nullptr,
       1.f, 0.f, 4, 64, 0);
  spmm(stream, i_off, i_csrc, f_cw, B4 + 64, 192, B4 + 128, 192, B4, 192, nullptr,
       2.f, -1.f, 4, 64, 0);
  gemm_v8_kernel<32, 48, true><<<dim3(20, 4, 4), 128, 0, stream>>>(
      B4, 192, W4, 128, P, NN, 192, 48, 128);
  reduce_bias_kernel<<<(NN * 128 + 255) / 256, 256, 0, stream>>>(
      P, H4, b4, NN, 128, 128, 4, 1);                                 // H4 (ld 128)

  // ---- Layer 5 (push-through, 128 -> 19 padded 20): ABC = H4 @ Wc5 ----
  gemm_v8_kernel<20, 32, true><<<dim3(20, 3, 4), 128, 0, stream>>>(
      H4, 128, wc5, 60, P, NN, 128, 32, 60);
  reduce_bias_kernel<<<(NN * 60 + 255) / 256, 256, 0, stream>>>(
      P, ABC5, nullptr, NN, 60, 60, 4, 0);
  // E5 = 2*L(C) + B   (C=8 chunks cover 32 cols; cols >= 20 masked at store)
  spmm(stream, i_off, i_csrc, f_cw, ABC5 + 40, 60, E5, 32, ABC5 + 20, 60, nullptr,
       2.f, 1.f, 3, 20, 0);
  // out = softmax(L(E5) + A + b5)  (ld 19, fused)
  spmm(stream, i_off, i_csrc, f_cw, E5, 32, out, 19, ABC5, 60, b5,
       1.f, 1.f, 3, 19, 0, 1);
}

// Round 9
// 324.538 us; speedup vs baseline: 1.3317x; 1.0651x over previous
//
#include <hip/hip_runtime.h>
#include <math.h>

#define NN 10000
#define NE 160000

// ---------------- CSR build (+ fused weight concat) ----------------

__device__ __forceinline__ void wcat_one(const float* __restrict__ W,
                                         float* __restrict__ Wc,
                                         int i, int Fin, int F, int Fp) {
  int w3 = 3 * Fp;
  int row = i / w3;
  int c = i - row * w3;
  int sec = c / Fp;
  int f = c - sec * Fp;
  float v = 0.0f;
  if (f < F) {
    if (sec == 0)      v = W[row * F + f] - W[2 * Fin * F + row * F + f];
    else if (sec == 1) v = W[Fin * F + row * F + f];
    else               v = W[2 * Fin * F + row * F + f];
  }
  Wc[i] = v;
}

#define WC1_TOTAL (782 * 48)
#define WC5_TOTAL (128 * 60)

// blocks cover NE edge slots, then wc1/wc5 elements (independent work fused)
__global__ __launch_bounds__(256) void deg_wcat_kernel(
    const int* __restrict__ src, const int* __restrict__ dst,
    int* __restrict__ deg, int* __restrict__ cnt,
    const float* __restrict__ W1, float* __restrict__ wc1,
    const float* __restrict__ W5, float* __restrict__ wc5) {
  int idx = blockIdx.x * 256 + threadIdx.x;
  if (idx < NE) {
    atomicAdd(&deg[src[idx]], 1);
    atomicAdd(&cnt[dst[idx]], 1);
  } else {
    int i = idx - NE;
    if (i < WC1_TOTAL) {
      wcat_one(W1, wc1, i, 782, 16, 16);
    } else if (i < WC1_TOTAL + WC5_TOTAL) {
      wcat_one(W5, wc5, i - WC1_TOTAL, 128, 19, 20);
    }
  }
}

// fused: dinv (from deg-by-src) + exclusive scan of cnt (by dst) -> off
__global__ __launch_bounds__(1024) void scan_dinv_kernel(const int* __restrict__ cnt,
                                                         int* __restrict__ off,
                                                         const int* __restrict__ deg,
                                                         float* __restrict__ dinv, int n) {
  __shared__ int sh[1024];
  int t = threadIdx.x;
  for (int i = t; i < n; i += 1024) {
    int d = deg[i];
    dinv[i] = d > 0 ? 1.0f / sqrtf((float)d) : 0.0f;
  }
  int per = (n + 1023) / 1024;
  int base = t * per;
  int sum = 0;
  for (int i = 0; i < per; i++) {
    int idx = base + i;
    if (idx < n) sum += cnt[idx];
  }
  sh[t] = sum;
  __syncthreads();
  for (int d = 1; d < 1024; d <<= 1) {
    int v = (t >= d) ? sh[t - d] : 0;
    __syncthreads();
    if (t >= d) sh[t] += v;
    __syncthreads();
  }
  int run = (t > 0) ? sh[t - 1] : 0;
  for (int i = 0; i < per; i++) {
    int idx = base + i;
    if (idx < n) { off[idx] = run; run += cnt[idx]; }
  }
  if (t == 0) off[n] = sh[1023];
}

__global__ __launch_bounds__(256) void fill_kernel(const int* __restrict__ src,
                                                   const int* __restrict__ dst,
                                                   const float* __restrict__ dinv,
                                                   const int* __restrict__ off,
                                                   int* __restrict__ pos,
                                                   int* __restrict__ csrc,
                                                   float* __restrict__ cw, int E) {
  int e = blockIdx.x * 256 + threadIdx.x;
  if (e < E) {
    int s = src[e], d = dst[e];
    int slot = off[d] + atomicAdd(&pos[d], 1);
    csrc[slot] = s;
    cw[slot] = -dinv[s] * dinv[d];
  }
}

// ---------------- GEMM v9: v8 + RT template (y=1 for L1 via RT=2) -----------
// 128 threads/block; thread t owns rows {t + i*128, i<RT}. X k-slices load
// straight into registers (double-buffered, named fields -> no scratch); W
// kchunk-slice staged to LDS once (one barrier), wave-uniform b128 broadcast.
// K-loop has no __syncthreads. Partials to P[z][M*Nd].

struct Row8 { float4 lo, hi; };  // 8 consecutive k-floats of one row

__device__ __forceinline__ Row8 zero8() {
  Row8 r;
  r.lo = make_float4(0.f, 0.f, 0.f, 0.f);
  r.hi = make_float4(0.f, 0.f, 0.f, 0.f);
  return r;
}

template <bool AL16>
__device__ __forceinline__ Row8 ld_row8(const float* __restrict__ X, int ldx,
                                        int gr, int M, int kc, int kend) {
  Row8 r = zero8();
  if (gr < M && kc < kend) {
    const float* xp = X + (size_t)gr * ldx + kc;
    if (kc + 8 <= kend) {
      if (AL16) {
        r.lo = ((const float4*)xp)[0];
        r.hi = ((const float4*)xp)[1];
      } else {  // rows only 8B-aligned (ldx=782, kc even)
        float2 a = *(const float2*)xp;
        float2 b = *(const float2*)(xp + 2);
        float2 c = *(const float2*)(xp + 4);
        float2 d = *(const float2*)(xp + 6);
        r.lo = make_float4(a.x, a.y, b.x, b.y);
        r.hi = make_float4(c.x, c.y, d.x, d.y);
      }
    } else {
      int rem = kend - kc;  // 1..7
      r.lo.x = xp[0];
      if (rem > 1) r.lo.y = xp[1];
      if (rem > 2) r.lo.z = xp[2];
      if (rem > 3) r.lo.w = xp[3];
      if (rem > 4) r.hi.x = xp[4];
      if (rem > 5) r.hi.y = xp[5];
      if (rem > 6) r.hi.z = xp[6];
    }
  }
  return r;
}

struct X4R { Row8 r0, r1, r2, r3; };

template <bool AL16, int RT>
__device__ __forceinline__ X4R ld_chunk(const float* __restrict__ X, int ldx,
                                        int row0, int t, int M, int kc, int kend) {
  X4R x;
  x.r0 = ld_row8<AL16>(X, ldx, row0 + t, M, kc, kend);
  if constexpr (RT > 1) x.r1 = ld_row8<AL16>(X, ldx, row0 + t + 128, M, kc, kend);
  else x.r1 = zero8();
  if constexpr (RT > 2) x.r2 = ld_row8<AL16>(X, ldx, row0 + t + 256, M, kc, kend);
  else x.r2 = zero8();
  if constexpr (RT > 3) x.r3 = ld_row8<AL16>(X, ldx, row0 + t + 384, M, kc, kend);
  else x.r3 = zero8();
  return x;
}

__device__ __forceinline__ float comp8(const Row8& r, int k) {  // k compile-time
  switch (k) {
    case 0: return r.lo.x; case 1: return r.lo.y;
    case 2: return r.lo.z; case 3: return r.lo.w;
    case 4: return r.hi.x; case 5: return r.hi.y;
    case 6: return r.hi.z; default: return r.hi.w;
  }
}

template <int TN, int MAXKC, bool AL16, int RT>
__global__ __launch_bounds__(128, 1) void gemm_v9_kernel(
    const float* __restrict__ X, int ldx,
    const float* __restrict__ W, int ldw,
    float* __restrict__ P,
    int M, int Kd, int kchunk, int Nd) {
  __shared__ float Ws[MAXKC * TN];
  int t = threadIdx.x;  // 0..127
  int row0 = blockIdx.x * (128 * RT);
  int col0 = blockIdx.y * TN;
  int k0 = blockIdx.z * kchunk;
  int kend = k0 + kchunk;
  if (kend > Kd) kend = Kd;
  P += (size_t)blockIdx.z * M * Nd;

  // ---- stage W slice [k0,kend) x TN once (zero-filled to MAXKC) ----
  constexpr int W4 = TN / 4;
  for (int idx = t; idx < MAXKC * W4; idx += 128) {
    int wk = idx / W4;
    int wc = (idx - wk * W4) * 4;
    float4 wv = make_float4(0.f, 0.f, 0.f, 0.f);
    if (k0 + wk < kend)
      wv = *(const float4*)(W + (size_t)(k0 + wk) * ldw + col0 + wc);
    *(float4*)(Ws + wk * TN + wc) = wv;
  }
  __syncthreads();  // the only barrier

  float acc0[TN], acc1[TN], acc2[TN], acc3[TN];
#pragma unroll
  for (int c = 0; c < TN; c++) { acc0[c] = 0.f; acc1[c] = 0.f; acc2[c] = 0.f; acc3[c] = 0.f; }

  int nchunks = (kend - k0 + 7) >> 3;
  X4R cur = ld_chunk<AL16, RT>(X, ldx, row0, t, M, k0, kend);
  for (int ci = 0; ci < nchunks; ci++) {
    X4R nxt = cur;
    if (ci + 1 < nchunks)
      nxt = ld_chunk<AL16, RT>(X, ldx, row0, t, M, k0 + (ci + 1) * 8, kend);
    int kb = ci << 3;
#pragma unroll
    for (int k = 0; k < 8; k++) {
      const float* wr = Ws + (kb + k) * TN;
      float x0 = comp8(cur.r0, k);
#pragma unroll
      for (int c = 0; c < TN; c += 4) {
        float4 wv = *(const float4*)(wr + c);  // wave-uniform -> LDS broadcast
        acc0[c + 0] += x0 * wv.x; acc0[c + 1] += x0 * wv.y;
        acc0[c + 2] += x0 * wv.z; acc0[c + 3] += x0 * wv.w;
      }
      if constexpr (RT > 1) {
        float x1 = comp8(cur.r1, k);
#pragma unroll
        for (int c = 0; c < TN; c += 4) {
          float4 wv = *(const float4*)(wr + c);
          acc1[c + 0] += x1 * wv.x; acc1[c + 1] += x1 * wv.y;
          acc1[c + 2] += x1 * wv.z; acc1[c + 3] += x1 * wv.w;
        }
      }
      if constexpr (RT > 2) {
        float x2 = comp8(cur.r2, k);
#pragma unroll
        for (int c = 0; c < TN; c += 4) {
          float4 wv = *(const float4*)(wr + c);
          acc2[c + 0] += x2 * wv.x; acc2[c + 1] += x2 * wv.y;
          acc2[c + 2] += x2 * wv.z; acc2[c + 3] += x2 * wv.w;
        }
      }
      if constexpr (RT > 3) {
        float x3 = comp8(cur.r3, k);
#pragma unroll
        for (int c = 0; c < TN; c += 4) {
          float4 wv = *(const float4*)(wr + c);
          acc3[c + 0] += x3 * wv.x; acc3[c + 1] += x3 * wv.y;
          acc3[c + 2] += x3 * wv.z; acc3[c + 3] += x3 * wv.w;
        }
      }
    }
    cur = nxt;
  }

  // ---- store partials (explicit per-row blocks) ----
  {
    int r = row0 + t;
    if (r < M) {
      float* pr = P + (size_t)r * Nd + col0;
#pragma unroll
      for (int c = 0; c < TN; c += 4)
        *(float4*)(pr + c) = make_float4(acc0[c], acc0[c + 1], acc0[c + 2], acc0[c + 3]);
    }
  }
  if constexpr (RT > 1) {
    int r = row0 + t + 128;
    if (r < M) {
      float* pr = P + (size_t)r * Nd + col0;
#pragma unroll
      for (int c = 0; c < TN; c += 4)
        *(float4*)(pr + c) = make_float4(acc1[c], acc1[c + 1], acc1[c + 2], acc1[c + 3]);
    }
  }
  if constexpr (RT > 2) {
    int r = row0 + t + 256;
    if (r < M) {
      float* pr = P + (size_t)r * Nd + col0;
#pragma unroll
      for (int c = 0; c < TN; c += 4)
        *(float4*)(pr + c) = make_float4(acc2[c], acc2[c + 1], acc2[c + 2], acc2[c + 3]);
    }
  }
  if constexpr (RT > 3) {
    int r = row0 + t + 384;
    if (r < M) {
      float* pr = P + (size_t)r * Nd + col0;
#pragma unroll
      for (int c = 0; c < TN; c += 4)
        *(float4*)(pr + c) = make_float4(acc3[c], acc3[c + 1], acc3[c + 2], acc3[c + 3]);
    }
  }
}

// fused k-split reduce + bias + relu: Y[r*ldy+c] = act(sum_j P[j][r*Nd+c] + bias[c])
__global__ __launch_bounds__(256) void reduce_bias_kernel(
    const float* __restrict__ P, float* __restrict__ Y,
    const float* __restrict__ bias,
    int M, int Nd, int ldy, int nsplit, int relu) {
  int i = blockIdx.x * 256 + threadIdx.x;
  int total = M * Nd;
  if (i >= total) return;
  float s = 0.f;
  for (int j = 0; j < nsplit; j++) s += P[(size_t)j * total + i];
  int r = i / Nd, c = i - r * Nd;
  if (bias) s += bias[c];
  if (relu) s = fmaxf(s, 0.f);
  Y[(size_t)r * ldy + c] = s;
}

// ---------------- SpMM: wave-per-node (optionally fused softmax) ------------
// Vectorized add-read and store (all non-softmax targets are 16B-aligned).

__global__ __launch_bounds__(256) void spmm_kernel(
    const int* __restrict__ off,
    const int* __restrict__ csrc,
    const float* __restrict__ cw,
    const float* __restrict__ X, int ldx,
    float* __restrict__ Y, int ldy,
    const float* __restrict__ add, int lda,
    const float* __restrict__ bias,
    float alpha, float beta,
    int n, int C_log2, int Fstore, int relu, int do_softmax) {
  int wave_in_blk = threadIdx.x >> 6;
  int lane = threadIdx.x & 63;
  int node = blockIdx.x * 4 + wave_in_blk;
  if (node >= n) return;
  int C = 1 << C_log2;
  int chunk = lane & (C - 1);
  int eslot = lane >> C_log2;
  int Epar = 64 >> C_log2;

  int j0 = off[node], j1 = off[node + 1];
  float sx = 0.f, sy = 0.f, sz = 0.f, sw = 0.f;
  for (int j = j0 + eslot; j < j1; j += Epar) {
    int sn = csrc[j];
    float w = cw[j];
    float4 xv = *(const float4*)(X + (size_t)sn * ldx + (chunk << 2));
    sx += w * xv.x; sy += w * xv.y; sz += w * xv.z; sw += w * xv.w;
  }
  for (int st = C; st < 64; st <<= 1) {
    sx += __shfl_xor(sx, st);
    sy += __shfl_xor(sy, st);
    sz += __shfl_xor(sz, st);
    sw += __shfl_xor(sw, st);
  }
  if (eslot == 0) {
    int f0 = chunk << 2;
    float4 u = make_float4(alpha * sx, alpha * sy, alpha * sz, alpha * sw);
    if (add) {
      float4 av = *(const float4*)(add + (size_t)node * lda + f0);  // in-bounds by layout
      u.x += beta * av.x; u.y += beta * av.y; u.z += beta * av.z; u.w += beta * av.w;
    }
    if (bias) {
      if (f0 + 0 < Fstore) u.x += bias[f0 + 0];
      if (f0 + 1 < Fstore) u.y += bias[f0 + 1];
      if (f0 + 2 < Fstore) u.z += bias[f0 + 2];
      if (f0 + 3 < Fstore) u.w += bias[f0 + 3];
    }
    if (!do_softmax) {
      if (relu) {
        u.x = fmaxf(u.x, 0.f); u.y = fmaxf(u.y, 0.f);
        u.z = fmaxf(u.z, 0.f); u.w = fmaxf(u.w, 0.f);
      }
      if (f0 + 4 <= Fstore) {
        *(float4*)(Y + (size_t)node * ldy + f0) = u;  // 16B-aligned by construction
      } else {
        float vv[4] = {u.x, u.y, u.z, u.w};
#pragma unroll
        for (int c = 0; c < 4; c++)
          if (f0 + c < Fstore) Y[(size_t)node * ldy + f0 + c] = vv[c];
      }
    } else {
      float v[4] = {u.x, u.y, u.z, u.w};
      float mx = -INFINITY;
#pragma unroll
      for (int c = 0; c < 4; c++)
        if (f0 + c < Fstore) mx = fmaxf(mx, v[c]);
      mx = fmaxf(mx, __shfl_xor(mx, 1));
      mx = fmaxf(mx, __shfl_xor(mx, 2));
      mx = fmaxf(mx, __shfl_xor(mx, 4));
      float e[4];
      float s = 0.f;
#pragma unroll
      for (int c = 0; c < 4; c++) {
        e[c] = (f0 + c < Fstore) ? __expf(v[c] - mx) : 0.f;
        s += e[c];
      }
      s += __shfl_xor(s, 1);
      s += __shfl_xor(s, 2);
      s += __shfl_xor(s, 4);
      float inv = 1.f / s;
#pragma unroll
      for (int c = 0; c < 4; c++) {
        int f = f0 + c;
        if (f < Fstore) Y[(size_t)node * ldy + f] = e[c] * inv;
      }
    }
  }
}

// ---------------- host orchestration ----------------

static void spmm(hipStream_t s, const int* off, const int* csrc, const float* cw,
                 const float* X, int ldx, float* Y, int ldy,
                 const float* add, int lda, const float* bias,
                 float alpha, float beta, int C_log2, int Fstore, int relu,
                 int do_softmax = 0) {
  spmm_kernel<<<(NN + 3) / 4, 256, 0, s>>>(off, csrc, cw, X, ldx, Y, ldy, add, lda,
                                           bias, alpha, beta, NN, C_log2, Fstore,
                                           relu, do_softmax);
}

extern "C" void kernel_launch(void* const* d_in, const int* in_sizes, int n_in,
                              void* d_out, int out_size, void* d_ws, size_t ws_size,
                              hipStream_t stream) {
  const float* x  = (const float*)d_in[0];
  const int*   ei = (const int*)d_in[1];
  const float* W1 = (const float*)d_in[2];
  const float* b1 = (const float*)d_in[3];
  const float* W2 = (const float*)d_in[4];
  const float* b2 = (const float*)d_in[5];
  const float* W3 = (const float*)d_in[6];
  const float* b3 = (const float*)d_in[7];
  const float* W4 = (const float*)d_in[8];
  const float* b4 = (const float*)d_in[9];
  const float* W5 = (const float*)d_in[10];
  const float* b5 = (const float*)d_in[11];
  float* out = (float*)d_out;
  const int* src = ei;
  const int* dst = ei + NE;
  (void)in_sizes; (void)n_in; (void)out_size; (void)ws_size;

  char* p = (char*)d_ws;
  auto alloc = [&](size_t bytes) {
    char* r = p;
    p += (bytes + 255) & ~(size_t)255;
    return r;
  };
  int*   i_deg  = (int*)alloc(sizeof(int) * NN * 3);  // deg, cnt, pos (one memset)
  int*   i_cnt  = i_deg + NN;
  int*   i_pos  = i_cnt + NN;
  float* f_dinv = (float*)alloc(sizeof(float) * NN);
  int*   i_off  = (int*)alloc(sizeof(int) * (NN + 1));
  int*   i_csrc = (int*)alloc(sizeof(int) * NE);
  float* f_cw   = (float*)alloc(sizeof(float) * NE);
  float* wc1    = (float*)alloc(sizeof(float) * 782 * 48);
  float* wc5    = (float*)alloc(sizeof(float) * 128 * 60);
  float* R1     = (float*)alloc(sizeof(float) * NN * 96);   // ABC1(48)->B3(96)->ABC5(60)
  float* R2     = (float*)alloc(sizeof(float) * NN * 192);  // E1(16)->B4(192)->E5(32)
  float* R3     = (float*)alloc(sizeof(float) * NN * 128);  // B2(48)->H4(128)
  float* P      = (float*)alloc(sizeof(float) * NN * 640);  // k-split partials (max 13x48)

  float* ABC1 = R1;
  float* E1   = R2;
  float* B2   = R3;
  float* B3   = R1;
  float* B4   = R2;
  float* H4   = R3;
  float* ABC5 = R1;
  float* E5   = R2;

  // ---- structure (deg/cnt atomics + both wcats in one launch) ----
  hipMemsetAsync(i_deg, 0, sizeof(int) * NN * 3, stream);
  deg_wcat_kernel<<<(NE + WC1_TOTAL + WC5_TOTAL + 255) / 256, 256, 0, stream>>>(
      src, dst, i_deg, i_cnt, W1, wc1, W5, wc5);
  scan_dinv_kernel<<<1, 1024, 0, stream>>>(i_cnt, i_off, i_deg, f_dinv, NN);
  fill_kernel<<<(NE + 255) / 256, 256, 0, stream>>>(src, dst, f_dinv, i_off, i_pos,
                                                    i_csrc, f_cw, NE);

  // ---- Layer 1 (push-through, 782 -> 16): ABC = X @ Wc1 ----
  // y=1 (X fetched ONCE), RT=2 (acc 96 + prefetch 32 VGPR), z=13 (kchunk 62)
  gemm_v9_kernel<48, 64, false, 2><<<dim3(40, 1, 13), 128, 0, stream>>>(
      x, 782, wc1, 48, P, NN, 782, 62, 48);
  reduce_bias_kernel<<<(NN * 48 + 255) / 256, 256, 0, stream>>>(
      P, ABC1, nullptr, NN, 48, 48, 13, 0);
  // E1 = 2*L(C) + B
  spmm(stream, i_off, i_csrc, f_cw, ABC1 + 32, 48, E1, 16, ABC1 + 16, 48, nullptr,
       2.f, 1.f, 2, 16, 0);
  // H1 = relu(L(E1) + A + b1) -> B2 slot0 (ld 48)
  spmm(stream, i_off, i_csrc, f_cw, E1, 16, B2, 48, ABC1, 48, b1,
       1.f, 1.f, 2, 16, 1);

  // ---- Layer 2 (fused standard, 16 -> 32): concat [T0|T1|T2] in B2 (ld 48) ----
  spmm(stream, i_off, i_csrc, f_cw, B2, 48, B2 + 16, 48, nullptr, 0, nullptr,
       1.f, 0.f, 2, 16, 0);                                           // T1
  spmm(stream, i_off, i_csrc, f_cw, B2 + 16, 48, B2 + 32, 48, B2, 48, nullptr,
       2.f, -1.f, 2, 16, 0);                                          // T2
  gemm_v9_kernel<16, 16, true, 4><<<dim3(20, 2, 3), 128, 0, stream>>>(
      B2, 48, W2, 32, P, NN, 48, 16, 32);
  reduce_bias_kernel<<<(NN * 32 + 255) / 256, 256, 0, stream>>>(
      P, B3, b2, NN, 32, 96, 3, 1);                                   // H2 -> B3 slot0

  // ---- Layer 3 (32 -> 64), concat in B3 (ld 96) ----
  spmm(stream, i_off, i_csrc, f_cw, B3, 96, B3 + 32, 96, nullptr, 0, nullptr,
       1.f, 0.f, 3, 32, 0);
  spmm(stream, i_off, i_csrc, f_cw, B3 + 32, 96, B3 + 64, 96, B3, 96, nullptr,
       2.f, -1.f, 3, 32, 0);
  gemm_v9_kernel<32, 32, true, 4><<<dim3(20, 2, 3), 128, 0, stream>>>(
      B3, 96, W3, 64, P, NN, 96, 32, 64);
  reduce_bias_kernel<<<(NN * 64 + 255) / 256, 256, 0, stream>>>(
      P, B4, b3, NN, 64, 192, 3, 1);                                  // H3 -> B4 slot0

  // ---- Layer 4 (64 -> 128), concat in B4 (ld 192) ----
  spmm(stream, i_off, i_csrc, f_cw, B4, 192, B4 + 64, 192, nullptr, 0, nullptr,
       1.f, 0.f, 4, 64, 0);
  spmm(stream, i_off, i_csrc, f_cw, B4 + 64, 192, B4 + 128, 192, B4, 192, nullptr,
       2.f, -1.f, 4, 64, 0);
  gemm_v9_kernel<32, 48, true, 4><<<dim3(20, 4, 4), 128, 0, stream>>>(
      B4, 192, W4, 128, P, NN, 192, 48, 128);
  reduce_bias_kernel<<<(NN * 128 + 255) / 256, 256, 0, stream>>>(
      P, H4, b4, NN, 128, 128, 4, 1);                                 // H4 (ld 128)

  // ---- Layer 5 (push-through, 128 -> 19 padded 20): ABC = H4 @ Wc5 ----
  gemm_v9_kernel<20, 32, true, 4><<<dim3(20, 3, 4), 128, 0, stream>>>(
      H4, 128, wc5, 60, P, NN, 128, 32, 60);
  reduce_bias_kernel<<<(NN * 60 + 255) / 256, 256, 0, stream>>>(
      P, ABC5, nullptr, NN, 60, 60, 4, 0);
  // E5 = 2*L(C) + B   (C=8 chunks cover 32 cols; cols >= 20 masked at store)
  spmm(stream, i_off, i_csrc, f_cw, ABC5 + 40, 60, E5, 32, ABC5 + 20, 60, nullptr,
       2.f, 1.f, 3, 20, 0);
  // out = softmax(L(E5) + A + b5)  (ld 19, fused)
  spmm(stream, i_off, i_csrc, f_cw, E5, 32, out, 19, ABC5, 60, b5,
       1.f, 1.f, 3, 19, 0, 1);
}

// Round 10
// 295.764 us; speedup vs baseline: 1.4612x; 1.0973x over previous
//
#include <hip/hip_runtime.h>
#include <math.h>

#define NN 10000
#define NE 160000
#define CAP 128   // bucket capacity per node; P(in-deg >= 128 | Poisson(16)) ~ 1e-60

// ---------------- build: count + bucket insert + fused weight concat ---------

__device__ __forceinline__ void wcat_one(const float* __restrict__ W,
                                         float* __restrict__ Wc,
                                         int i, int Fin, int F, int Fp) {
  int w3 = 3 * Fp;
  int row = i / w3;
  int c = i - row * w3;
  int sec = c / Fp;
  int f = c - sec * Fp;
  float v = 0.0f;
  if (f < F) {
    if (sec == 0)      v = W[row * F + f] - W[2 * Fin * F + row * F + f];
    else if (sec == 1) v = W[Fin * F + row * F + f];
    else               v = W[2 * Fin * F + row * F + f];
  }
  Wc[i] = v;
}

#define WC1_TOTAL (782 * 48)
#define WC5_TOTAL (128 * 60)

__global__ __launch_bounds__(256) void count_kernel(
    const int* __restrict__ src, const int* __restrict__ dst,
    int* __restrict__ deg, int* __restrict__ cnt,
    int* __restrict__ bsrc,
    const float* __restrict__ W1, float* __restrict__ wc1,
    const float* __restrict__ W5, float* __restrict__ wc5) {
  int idx = blockIdx.x * 256 + threadIdx.x;
  if (idx < NE) {
    int s = src[idx], d = dst[idx];
    atomicAdd(&deg[s], 1);
    int slot = atomicAdd(&cnt[d], 1);
    if (slot < CAP) bsrc[(d << 7) + slot] = s;
  } else {
    int i = idx - NE;
    if (i < WC1_TOTAL) {
      wcat_one(W1, wc1, i, 782, 16, 16);
    } else if (i < WC1_TOTAL + WC5_TOTAL) {
      wcat_one(W5, wc5, i - WC1_TOTAL, 128, 19, 20);
    }
  }
}

// per-bucket-slot: bw = -dinv(src) * dinv(dst), straight from final deg
__global__ __launch_bounds__(256) void bw_kernel(
    const int* __restrict__ deg, const int* __restrict__ cnt,
    const int* __restrict__ bsrc, float* __restrict__ bw) {
  int idx = blockIdx.x * 256 + threadIdx.x;  // over NN*CAP
  int node = idx >> 7;
  int slot = idx & (CAP - 1);
  if (node >= NN) return;
  int cn = cnt[node]; if (cn > CAP) cn = CAP;
  if (slot < cn) {
    int s = bsrc[idx];
    int ds = deg[s];            // >= 1 (s occurs as src)
    int dn = deg[node];
    float a = 1.0f / sqrtf((float)ds);
    float b = dn > 0 ? 1.0f / sqrtf((float)dn) : 0.0f;
    bw[idx] = -a * b;
  }
}

// ---------------- GEMM v10: register-X prefetch, LDS-W broadcast -------------
// 128 threads/block; thread t owns rows {t + i*128, i<RT}. X k-slices load
// straight into registers (double-buffered, named fields). W slice in LDS
// (one barrier), wave-uniform b128 broadcast. DIRECT: fused bias/relu write
// to Y(ldy); else k-split partials P[z][M*Nd].

struct Row8 { float4 lo, hi; };

__device__ __forceinline__ Row8 zero8() {
  Row8 r;
  r.lo = make_float4(0.f, 0.f, 0.f, 0.f);
  r.hi = make_float4(0.f, 0.f, 0.f, 0.f);
  return r;
}

template <bool AL16>
__device__ __forceinline__ Row8 ld_row8(const float* __restrict__ X, int ldx,
                                        int gr, int M, int kc, int kend) {
  Row8 r = zero8();
  if (gr < M && kc < kend) {
    const float* xp = X + (size_t)gr * ldx + kc;
    if (kc + 8 <= kend) {
      if (AL16) {
        r.lo = ((const float4*)xp)[0];
        r.hi = ((const float4*)xp)[1];
      } else {  // rows only 8B-aligned (ldx=782, kc even)
        float2 a = *(const float2*)xp;
        float2 b = *(const float2*)(xp + 2);
        float2 c = *(const float2*)(xp + 4);
        float2 d = *(const float2*)(xp + 6);
        r.lo = make_float4(a.x, a.y, b.x, b.y);
        r.hi = make_float4(c.x, c.y, d.x, d.y);
      }
    } else {
      int rem = kend - kc;  // 1..7
      r.lo.x = xp[0];
      if (rem > 1) r.lo.y = xp[1];
      if (rem > 2) r.lo.z = xp[2];
      if (rem > 3) r.lo.w = xp[3];
      if (rem > 4) r.hi.x = xp[4];
      if (rem > 5) r.hi.y = xp[5];
      if (rem > 6) r.hi.z = xp[6];
    }
  }
  return r;
}

struct X4R { Row8 r0, r1, r2, r3; };

template <bool AL16, int RT>
__device__ __forceinline__ X4R ld_chunk(const float* __restrict__ X, int ldx,
                                        int row0, int t, int M, int kc, int kend) {
  X4R x;
  x.r0 = ld_row8<AL16>(X, ldx, row0 + t, M, kc, kend);
  if constexpr (RT > 1) x.r1 = ld_row8<AL16>(X, ldx, row0 + t + 128, M, kc, kend);
  else x.r1 = zero8();
  if constexpr (RT > 2) x.r2 = ld_row8<AL16>(X, ldx, row0 + t + 256, M, kc, kend);
  else x.r2 = zero8();
  if constexpr (RT > 3) x.r3 = ld_row8<AL16>(X, ldx, row0 + t + 384, M, kc, kend);
  else x.r3 = zero8();
  return x;
}

__device__ __forceinline__ float comp8(const Row8& r, int k) {
  switch (k) {
    case 0: return r.lo.x; case 1: return r.lo.y;
    case 2: return r.lo.z; case 3: return r.lo.w;
    case 4: return r.hi.x; case 5: return r.hi.y;
    case 6: return r.hi.z; default: return r.hi.w;
  }
}

template <int TN, int MAXKC, bool AL16, int RT, bool DIRECT>
__global__ __launch_bounds__(128, 1) void gemm_v10_kernel(
    const float* __restrict__ X, int ldx,
    const float* __restrict__ W, int ldw,
    float* __restrict__ Y,
    const float* __restrict__ bias, int relu, int ldy,
    int M, int Kd, int kchunk, int Nd) {
  __shared__ float Ws[MAXKC * TN];
  int t = threadIdx.x;  // 0..127
  int row0 = blockIdx.x * (128 * RT);
  int col0 = blockIdx.y * TN;
  int k0 = blockIdx.z * kchunk;
  int kend = k0 + kchunk;
  if (kend > Kd) kend = Kd;
  if (!DIRECT) Y += (size_t)blockIdx.z * M * Nd;

  constexpr int W4 = TN / 4;
  for (int idx = t; idx < MAXKC * W4; idx += 128) {
    int wk = idx / W4;
    int wc = (idx - wk * W4) * 4;
    float4 wv = make_float4(0.f, 0.f, 0.f, 0.f);
    if (k0 + wk < kend)
      wv = *(const float4*)(W + (size_t)(k0 + wk) * ldw + col0 + wc);
    *(float4*)(Ws + wk * TN + wc) = wv;
  }
  __syncthreads();  // the only barrier

  float acc0[TN], acc1[TN], acc2[TN], acc3[TN];
#pragma unroll
  for (int c = 0; c < TN; c++) { acc0[c] = 0.f; acc1[c] = 0.f; acc2[c] = 0.f; acc3[c] = 0.f; }

  int nchunks = (kend - k0 + 7) >> 3;
  X4R cur = ld_chunk<AL16, RT>(X, ldx, row0, t, M, k0, kend);
  for (int ci = 0; ci < nchunks; ci++) {
    X4R nxt = cur;
    if (ci + 1 < nchunks)
      nxt = ld_chunk<AL16, RT>(X, ldx, row0, t, M, k0 + (ci + 1) * 8, kend);
    int kb = ci << 3;
#pragma unroll
    for (int k = 0; k < 8; k++) {
      const float* wr = Ws + (kb + k) * TN;
      float x0 = comp8(cur.r0, k);
#pragma unroll
      for (int c = 0; c < TN; c += 4) {
        float4 wv = *(const float4*)(wr + c);  // wave-uniform -> LDS broadcast
        acc0[c + 0] += x0 * wv.x; acc0[c + 1] += x0 * wv.y;
        acc0[c + 2] += x0 * wv.z; acc0[c + 3] += x0 * wv.w;
      }
      if constexpr (RT > 1) {
        float x1 = comp8(cur.r1, k);
#pragma unroll
        for (int c = 0; c < TN; c += 4) {
          float4 wv = *(const float4*)(wr + c);
          acc1[c + 0] += x1 * wv.x; acc1[c + 1] += x1 * wv.y;
          acc1[c + 2] += x1 * wv.z; acc1[c + 3] += x1 * wv.w;
        }
      }
      if constexpr (RT > 2) {
        float x2 = comp8(cur.r2, k);
#pragma unroll
        for (int c = 0; c < TN; c += 4) {
          float4 wv = *(const float4*)(wr + c);
          acc2[c + 0] += x2 * wv.x; acc2[c + 1] += x2 * wv.y;
          acc2[c + 2] += x2 * wv.z; acc2[c + 3] += x2 * wv.w;
        }
      }
      if constexpr (RT > 3) {
        float x3 = comp8(cur.r3, k);
#pragma unroll
        for (int c = 0; c < TN; c += 4) {
          float4 wv = *(const float4*)(wr + c);
          acc3[c + 0] += x3 * wv.x; acc3[c + 1] += x3 * wv.y;
          acc3[c + 2] += x3 * wv.z; acc3[c + 3] += x3 * wv.w;
        }
      }
    }
    cur = nxt;
  }

  // ---- epilogue ----
#pragma unroll
  for (int h = 0; h < RT; h++) {
    int r = row0 + t + h * 128;
    if (r < M) {
      float* acc = (h == 0) ? acc0 : (h == 1) ? acc1 : (h == 2) ? acc2 : acc3;
      if (DIRECT) {
        float* yr = Y + (size_t)r * ldy + col0;
#pragma unroll
        for (int c = 0; c < TN; c += 4) {
          float4 v;
          v.x = acc[c + 0] + (bias ? bias[col0 + c + 0] : 0.f);
          v.y = acc[c + 1] + (bias ? bias[col0 + c + 1] : 0.f);
          v.z = acc[c + 2] + (bias ? bias[col0 + c + 2] : 0.f);
          v.w = acc[c + 3] + (bias ? bias[col0 + c + 3] : 0.f);
          if (relu) {
            v.x = fmaxf(v.x, 0.f); v.y = fmaxf(v.y, 0.f);
            v.z = fmaxf(v.z, 0.f); v.w = fmaxf(v.w, 0.f);
          }
          *(float4*)(yr + c) = v;
        }
      } else {
        float* pr = Y + (size_t)r * Nd + col0;
#pragma unroll
        for (int c = 0; c < TN; c += 4)
          *(float4*)(pr + c) = make_float4(acc[c], acc[c + 1], acc[c + 2], acc[c + 3]);
      }
    }
  }
}

// fused k-split reduce + bias + relu
__global__ __launch_bounds__(256) void reduce_bias_kernel(
    const float* __restrict__ P, float* __restrict__ Y,
    const float* __restrict__ bias,
    int M, int Nd, int ldy, int nsplit, int relu) {
  int i = blockIdx.x * 256 + threadIdx.x;
  int total = M * Nd;
  if (i >= total) return;
  float s = 0.f;
  for (int j = 0; j < nsplit; j++) s += P[(size_t)j * total + i];
  int r = i / Nd, c = i - r * Nd;
  if (bias) s += bias[c];
  if (relu) s = fmaxf(s, 0.f);
  Y[(size_t)r * ldy + c] = s;
}

// ---------------- SpMM: wave-per-node over buckets (optional softmax) -------

__global__ __launch_bounds__(256) void spmm_kernel(
    const int* __restrict__ cnt,
    const int* __restrict__ bsrc,
    const float* __restrict__ bw,
    const float* __restrict__ X, int ldx,
    float* __restrict__ Y, int ldy,
    const float* __restrict__ add, int lda,
    const float* __restrict__ bias,
    float alpha, float beta,
    int n, int C_log2, int Fstore, int relu, int do_softmax) {
  int wave_in_blk = threadIdx.x >> 6;
  int lane = threadIdx.x & 63;
  int node = blockIdx.x * 4 + wave_in_blk;
  if (node >= n) return;
  int C = 1 << C_log2;
  int chunk = lane & (C - 1);
  int eslot = lane >> C_log2;
  int Epar = 64 >> C_log2;

  int j0 = node << 7;
  int cn = cnt[node]; if (cn > CAP) cn = CAP;
  int j1 = j0 + cn;
  float sx = 0.f, sy = 0.f, sz = 0.f, sw = 0.f;
  for (int j = j0 + eslot; j < j1; j += Epar) {
    int sn = bsrc[j];
    float w = bw[j];
    float4 xv = *(const float4*)(X + (size_t)sn * ldx + (chunk << 2));
    sx += w * xv.x; sy += w * xv.y; sz += w * xv.z; sw += w * xv.w;
  }
  for (int st = C; st < 64; st <<= 1) {
    sx += __shfl_xor(sx, st);
    sy += __shfl_xor(sy, st);
    sz += __shfl_xor(sz, st);
    sw += __shfl_xor(sw, st);
  }
  if (eslot == 0) {
    int f0 = chunk << 2;
    float4 u = make_float4(alpha * sx, alpha * sy, alpha * sz, alpha * sw);
    if (add) {
      float4 av = *(const float4*)(add + (size_t)node * lda + f0);
      u.x += beta * av.x; u.y += beta * av.y; u.z += beta * av.z; u.w += beta * av.w;
    }
    if (bias) {
      if (f0 + 0 < Fstore) u.x += bias[f0 + 0];
      if (f0 + 1 < Fstore) u.y += bias[f0 + 1];
      if (f0 + 2 < Fstore) u.z += bias[f0 + 2];
      if (f0 + 3 < Fstore) u.w += bias[f0 + 3];
    }
    if (!do_softmax) {
      if (relu) {
        u.x = fmaxf(u.x, 0.f); u.y = fmaxf(u.y, 0.f);
        u.z = fmaxf(u.z, 0.f); u.w = fmaxf(u.w, 0.f);
      }
      if (f0 + 4 <= Fstore) {
        *(float4*)(Y + (size_t)node * ldy + f0) = u;
      } else {
        float vv[4] = {u.x, u.y, u.z, u.w};
#pragma unroll
        for (int c = 0; c < 4; c++)
          if (f0 + c < Fstore) Y[(size_t)node * ldy + f0 + c] = vv[c];
      }
    } else {
      float v[4] = {u.x, u.y, u.z, u.w};
      float mx = -INFINITY;
#pragma unroll
      for (int c = 0; c < 4; c++)
        if (f0 + c < Fstore) mx = fmaxf(mx, v[c]);
      mx = fmaxf(mx, __shfl_xor(mx, 1));
      mx = fmaxf(mx, __shfl_xor(mx, 2));
      mx = fmaxf(mx, __shfl_xor(mx, 4));
      float e[4];
      float s = 0.f;
#pragma unroll
      for (int c = 0; c < 4; c++) {
        e[c] = (f0 + c < Fstore) ? __expf(v[c] - mx) : 0.f;
        s += e[c];
      }
      s += __shfl_xor(s, 1);
      s += __shfl_xor(s, 2);
      s += __shfl_xor(s, 4);
      float inv = 1.f / s;
#pragma unroll
      for (int c = 0; c < 4; c++) {
        int f = f0 + c;
        if (f < Fstore) Y[(size_t)node * ldy + f] = e[c] * inv;
      }
    }
  }
}

// ---------------- host orchestration ----------------

static void spmm(hipStream_t s, const int* cnt, const int* bsrc, const float* bw,
                 const float* X, int ldx, float* Y, int ldy,
                 const float* add, int lda, const float* bias,
                 float alpha, float beta, int C_log2, int Fstore, int relu,
                 int do_softmax = 0) {
  spmm_kernel<<<(NN + 3) / 4, 256, 0, s>>>(cnt, bsrc, bw, X, ldx, Y, ldy, add, lda,
                                           bias, alpha, beta, NN, C_log2, Fstore,
                                           relu, do_softmax);
}

extern "C" void kernel_launch(void* const* d_in, const int* in_sizes, int n_in,
                              void* d_out, int out_size, void* d_ws, size_t ws_size,
                              hipStream_t stream) {
  const float* x  = (const float*)d_in[0];
  const int*   ei = (const int*)d_in[1];
  const float* W1 = (const float*)d_in[2];
  const float* b1 = (const float*)d_in[3];
  const float* W2 = (const float*)d_in[4];
  const float* b2 = (const float*)d_in[5];
  const float* W3 = (const float*)d_in[6];
  const float* b3 = (const float*)d_in[7];
  const float* W4 = (const float*)d_in[8];
  const float* b4 = (const float*)d_in[9];
  const float* W5 = (const float*)d_in[10];
  const float* b5 = (const float*)d_in[11];
  float* out = (float*)d_out;
  const int* src = ei;
  const int* dst = ei + NE;
  (void)in_sizes; (void)n_in; (void)out_size; (void)ws_size;

  char* p = (char*)d_ws;
  auto alloc = [&](size_t bytes) {
    char* r = p;
    p += (bytes + 255) & ~(size_t)255;
    return r;
  };
  int*   i_deg  = (int*)alloc(sizeof(int) * NN * 2);  // deg, cnt (one memset)
  int*   i_cnt  = i_deg + NN;
  int*   i_bsrc = (int*)alloc(sizeof(int) * NN * CAP);
  float* f_bw   = (float*)alloc(sizeof(float) * NN * CAP);
  float* wc1    = (float*)alloc(sizeof(float) * 782 * 48);
  float* wc5    = (float*)alloc(sizeof(float) * 128 * 60);
  float* R1     = (float*)alloc(sizeof(float) * NN * 96);   // ABC1(48)->B3(96)->ABC5(60)
  float* R2     = (float*)alloc(sizeof(float) * NN * 192);  // E1(16)->B4(192)->E5(32)
  float* R3     = (float*)alloc(sizeof(float) * NN * 128);  // B2(48)->H4(128)
  float* P      = (float*)alloc(sizeof(float) * NN * 640);  // k-split partials

  float* ABC1 = R1;
  float* E1   = R2;
  float* B2   = R3;
  float* B3   = R1;
  float* B4   = R2;
  float* H4   = R3;
  float* ABC5 = R1;
  float* E5   = R2;

  // ---- structure: memset -> count(+wcat) -> bw ----
  hipMemsetAsync(i_deg, 0, sizeof(int) * NN * 2, stream);
  count_kernel<<<(NE + WC1_TOTAL + WC5_TOTAL + 255) / 256, 256, 0, stream>>>(
      src, dst, i_deg, i_cnt, i_bsrc, W1, wc1, W5, wc5);
  bw_kernel<<<(NN * CAP + 255) / 256, 256, 0, stream>>>(i_deg, i_cnt, i_bsrc, f_bw);

  // ---- Layer 1 (push-through, 782 -> 16): ABC = X @ Wc1, split-K ----
  gemm_v10_kernel<48, 64, false, 2, false><<<dim3(40, 1, 13), 128, 0, stream>>>(
      x, 782, wc1, 48, P, nullptr, 0, 0, NN, 782, 62, 48);
  reduce_bias_kernel<<<(NN * 48 + 255) / 256, 256, 0, stream>>>(
      P, ABC1, nullptr, NN, 48, 48, 13, 0);
  // E1 = 2*L(C) + B
  spmm(stream, i_cnt, i_bsrc, f_bw, ABC1 + 32, 48, E1, 16, ABC1 + 16, 48, nullptr,
       2.f, 1.f, 2, 16, 0);
  // H1 = relu(L(E1) + A + b1) -> B2 slot0 (ld 48)
  spmm(stream, i_cnt, i_bsrc, f_bw, E1, 16, B2, 48, ABC1, 48, b1,
       1.f, 1.f, 2, 16, 1);

  // ---- Layer 2 (standard, 16 -> 32): concat [T0|T1|T2] in B2 (ld 48) ----
  spmm(stream, i_cnt, i_bsrc, f_bw, B2, 48, B2 + 16, 48, nullptr, 0, nullptr,
       1.f, 0.f, 2, 16, 0);                                           // T1
  spmm(stream, i_cnt, i_bsrc, f_bw, B2 + 16, 48, B2 + 32, 48, B2, 48, nullptr,
       2.f, -1.f, 2, 16, 0);                                          // T2
  // H2 = relu(B2 @ W2 + b2) direct -> B3 slot0 (ld 96)
  gemm_v10_kernel<16, 48, true, 1, true><<<dim3(79, 2, 1), 128, 0, stream>>>(
      B2, 48, W2, 32, B3, b2, 1, 96, NN, 48, 48, 32);

  // ---- Layer 3 (32 -> 64), concat in B3 (ld 96) ----
  spmm(stream, i_cnt, i_bsrc, f_bw, B3, 96, B3 + 32, 96, nullptr, 0, nullptr,
       1.f, 0.f, 3, 32, 0);
  spmm(stream, i_cnt, i_bsrc, f_bw, B3 + 32, 96, B3 + 64, 96, B3, 96, nullptr,
       2.f, -1.f, 3, 32, 0);
  // H3 = relu(B3 @ W3 + b3) direct -> B4 slot0 (ld 192)
  gemm_v10_kernel<32, 96, true, 1, true><<<dim3(79, 2, 1), 128, 0, stream>>>(
      B3, 96, W3, 64, B4, b3, 1, 192, NN, 96, 96, 64);

  // ---- Layer 4 (64 -> 128), concat in B4 (ld 192), split-K ----
  spmm(stream, i_cnt, i_bsrc, f_bw, B4, 192, B4 + 64, 192, nullptr, 0, nullptr,
       1.f, 0.f, 4, 64, 0);
  spmm(stream, i_cnt, i_bsrc, f_bw, B4 + 64, 192, B4 + 128, 192, B4, 192, nullptr,
       2.f, -1.f, 4, 64, 0);
  gemm_v10_kernel<32, 48, true, 4, false><<<dim3(20, 4, 4), 128, 0, stream>>>(
      B4, 192, W4, 128, P, nullptr, 0, 0, NN, 192, 48, 128);
  reduce_bias_kernel<<<(NN * 128 + 255) / 256, 256, 0, stream>>>(
      P, H4, b4, NN, 128, 128, 4, 1);                                 // H4 (ld 128)

  // ---- Layer 5 (push-through, 128 -> 19 padded 20): ABC = H4 @ Wc5 direct ----
  gemm_v10_kernel<20, 128, true, 1, true><<<dim3(79, 3, 1), 128, 0, stream>>>(
      H4, 128, wc5, 60, ABC5, nullptr, 0, 60, NN, 128, 128, 60);
  // E5 = 2*L(C) + B   (C=8 chunks cover 32 cols; cols >= 20 masked at store)
  spmm(stream, i_cnt, i_bsrc, f_bw, ABC5 + 40, 60, E5, 32, ABC5 + 20, 60, nullptr,
       2.f, 1.f, 3, 20, 0);
  // out = softmax(L(E5) + A + b5)  (ld 19, fused)
  spmm(stream, i_cnt, i_bsrc, f_bw, E5, 32, out, 19, ABC5, 60, b5,
       1.f, 1.f, 3, 19, 0, 1);
}